// Round 2
// baseline (892.814 us; speedup 1.0000x reference)
//
#include <hip/hip_runtime.h>

#define N_PIX 16384   // 128*128
#define CC    192
#define C3    576
#define KK    192     // GEMM K (=CC)
#define HD    24

typedef __attribute__((ext_vector_type(8))) short short8;   // 8 bf16 = 4 VGPR
typedef __attribute__((ext_vector_type(4))) float f32x4;    // MFMA acc

__device__ __forceinline__ unsigned short f2bf(float x) {
    unsigned u = __float_as_uint(x);
    u += 0x7fff + ((u >> 16) & 1);          // round-to-nearest-even
    return (unsigned short)(u >> 16);
}
__device__ __forceinline__ float bf2f(unsigned short s) {
    return __uint_as_float(((unsigned)s) << 16);
}
__device__ __forceinline__ int pack2(unsigned short lo, unsigned short hi) {
    return (int)(((unsigned)hi << 16) | (unsigned)lo);
}

// K0: fp32 -> bf16 bulk convert (vector of 4)
__global__ __launch_bounds__(256) void cvt_f32_bf16(const float* __restrict__ src,
                                                    unsigned short* __restrict__ dst, int n4) {
    int i = blockIdx.x * 256 + threadIdx.x;
    if (i < n4) {
        float4 v = ((const float4*)src)[i];
        ushort4 o;
        o.x = f2bf(v.x); o.y = f2bf(v.y); o.z = f2bf(v.z); o.w = f2bf(v.w);
        ((ushort4*)dst)[i] = o;
    }
}

// ---------------------------------------------------------------------------
// bf16 MFMA GEMM body: C[m0+192, n0+128] = A[*,192] @ B[192, N_PIX]
// 256 threads = 4 waves (2x2), wave tile 96x64, 16x16x32 bf16 MFMA.
// A: bf16 row-major [M][192]. B: fp32 or bf16 [192][N_PIX]. C: bf16 or fp32.
// v3: register-prefetch pipeline (issue tile t+1 loads before tile t MFMAs);
//     LDS pad +12 (88B stride) -> writes 2-way (free), reads conflict-free.
// ---------------------------------------------------------------------------
template<bool B_F32, bool C_BF16>
__device__ __forceinline__ void mfma_gemm(const unsigned short* __restrict__ Abf,
                                          const void* __restrict__ Bsrc,
                                          void* __restrict__ Cdst,
                                          int m0, int n0) {
    __shared__ unsigned short As[192][44];   // [m][k]
    __shared__ unsigned short Bs[128][44];   // [n][k]

    const int tid  = threadIdx.x;
    const int wave = tid >> 6, lane = tid & 63;
    const int quad = lane >> 4, l15 = lane & 15;
    const int wr = wave >> 1, wc = wave & 1;

    f32x4 acc[6][4];
#pragma unroll
    for (int i = 0; i < 6; i++)
#pragma unroll
        for (int j = 0; j < 4; j++) acc[i][j] = (f32x4)0.f;

    const int kq = tid & 3;        // B staging: k-chunk (kq*8)
    const int nq = tid >> 2;       // B staging: n-pair (nq*2)

    // prefetch registers (live across the MFMA section)
    int4    areg[3];
    float2  bf32[8];
    ushort2 bb16[8];

    auto load_tile = [&](int k0) {
#pragma unroll
        for (int c = 0; c < 3; c++) {
            int ch  = tid + c * 256;
            int row = ch >> 2, kc = (ch & 3) * 8;
            areg[c] = *(const int4*)(Abf + (long)(m0 + row) * KK + k0 + kc);
        }
        if (B_F32) {
            const float* Bp = (const float*)Bsrc;
#pragma unroll
            for (int j = 0; j < 8; j++)
                bf32[j] = *(const float2*)(Bp + (long)(k0 + kq * 8 + j) * N_PIX + n0 + nq * 2);
        } else {
            const unsigned short* Bp = (const unsigned short*)Bsrc;
#pragma unroll
            for (int j = 0; j < 8; j++)
                bb16[j] = *(const ushort2*)(Bp + (long)(k0 + kq * 8 + j) * N_PIX + n0 + nq * 2);
        }
    };

    auto store_tile = [&]() {
#pragma unroll
        for (int c = 0; c < 3; c++) {
            int ch  = tid + c * 256;
            int row = ch >> 2, kc = (ch & 3) * 8;
            *(int4*)&As[row][kc] = areg[c];
        }
#pragma unroll
        for (int i = 0; i < 2; i++) {
            unsigned short us[8];
#pragma unroll
            for (int j = 0; j < 8; j++)
                us[j] = B_F32 ? f2bf(i ? bf32[j].y : bf32[j].x)
                              : (unsigned short)(i ? bb16[j].y : bb16[j].x);
            int4 pk = make_int4(pack2(us[0], us[1]), pack2(us[2], us[3]),
                                pack2(us[4], us[5]), pack2(us[6], us[7]));
            *(int4*)&Bs[nq * 2 + i][kq * 8] = pk;
        }
    };

    load_tile(0);                       // prologue: tile 0 in flight
    const int NIT = KK / 32;
    for (int it = 0; it < NIT; ++it) {
        store_tile();                   // waits vmcnt on use; convert + LDS write
        __syncthreads();
        if (it + 1 < NIT) load_tile((it + 1) * 32);   // issue next tile's loads

        short8 a[6], b[4];
#pragma unroll
        for (int mi = 0; mi < 6; mi++)
            a[mi] = *(const short8*)&As[wr * 96 + mi * 16 + l15][quad * 8];
#pragma unroll
        for (int ni = 0; ni < 4; ni++)
            b[ni] = *(const short8*)&Bs[wc * 64 + ni * 16 + l15][quad * 8];
#pragma unroll
        for (int mi = 0; mi < 6; mi++)
#pragma unroll
            for (int ni = 0; ni < 4; ni++)
                acc[mi][ni] = __builtin_amdgcn_mfma_f32_16x16x32_bf16(a[mi], b[ni], acc[mi][ni], 0, 0, 0);
        __syncthreads();                // protect LDS before next store_tile
    }

    // ---- epilogue: C/D layout col=lane&15, row=quad*4+reg ----
#pragma unroll
    for (int mi = 0; mi < 6; mi++)
#pragma unroll
        for (int ni = 0; ni < 4; ni++)
#pragma unroll
            for (int r = 0; r < 4; r++) {
                int row = m0 + wr * 96 + mi * 16 + quad * 4 + r;
                int col = n0 + wc * 64 + ni * 16 + l15;
                if (C_BF16)
                    ((unsigned short*)Cdst)[(long)row * N_PIX + col] = f2bf(acc[mi][ni][r]);
                else
                    ((float*)Cdst)[(long)row * N_PIX + col] = acc[mi][ni][r];
            }
}

// K1: Y[z][576,N] = w_bf[576,192] @ x[z][192,N]   (z = mod*8+b), bf16 out
__global__ __launch_bounds__(256, 2) void qkv_mfma(const unsigned short* __restrict__ wbf,
                                                   const float* __restrict__ rgb,
                                                   const float* __restrict__ ir,
                                                   unsigned short* __restrict__ Ybf) {
    const int z = blockIdx.z, mod = z >> 3, b = z & 7;
    const float* x = (mod ? ir : rgb) + (long)b * CC * N_PIX;
    unsigned short* y = Ybf + (long)z * C3 * N_PIX;
    mfma_gemm<true, true>(wbf, x, y, blockIdx.y * 192, blockIdx.x * 128);
}

// K5: out[z][192,N] = weff_bf[z][192,192] @ V[z][192,N], fp32 out
__global__ __launch_bounds__(256, 2) void out_mfma(const unsigned short* __restrict__ weff,
                                                   const unsigned short* __restrict__ Zbf,
                                                   float* __restrict__ out) {
    const int z = blockIdx.z;   // o*8+b; V modality == o
    const unsigned short* V = Zbf + ((long)z * C3 + 2 * CC) * N_PIX;
    float* C = out + (long)z * CC * N_PIX;
    mfma_gemm<false, false>(weff + (long)z * CC * CC, V, C, 0, blockIdx.x * 128);
}

// K2 v2: depthwise 3x3 SAME, bf16 in/out, 8 px/thread, vector loads + lane shuffles.
__global__ __launch_bounds__(256) void dwconv3x3(const unsigned short* __restrict__ Ybf,
                                                 const float* __restrict__ wdw,
                                                 unsigned short* __restrict__ Zbf) {
    const int z  = blockIdx.z;
    const int oc = blockIdx.y;
    const int idx = blockIdx.x * 256 + threadIdx.x;   // 0..2047
    const int p0  = idx * 8;
    const int h   = p0 >> 7;
    const int w0  = p0 & 127;
    const int wq  = threadIdx.x & 15;                 // == w0/8
    const unsigned short* Yc = Ybf + ((long)z * C3 + oc) * N_PIX;

    float wk[9];
#pragma unroll
    for (int i = 0; i < 9; i++) wk[i] = wdw[oc * 9 + i];

    float f[3][8];
#pragma unroll
    for (int ry = 0; ry < 3; ry++) {
        const int hy = h + ry - 1;
        int4 raw = make_int4(0, 0, 0, 0);
        if (hy >= 0 && hy <= 127)
            raw = *(const int4*)(Yc + hy * 128 + w0);
        f[ry][0] = bf2f((unsigned short)(raw.x & 0xffff));
        f[ry][1] = bf2f((unsigned short)((unsigned)raw.x >> 16));
        f[ry][2] = bf2f((unsigned short)(raw.y & 0xffff));
        f[ry][3] = bf2f((unsigned short)((unsigned)raw.y >> 16));
        f[ry][4] = bf2f((unsigned short)(raw.z & 0xffff));
        f[ry][5] = bf2f((unsigned short)((unsigned)raw.z >> 16));
        f[ry][6] = bf2f((unsigned short)(raw.w & 0xffff));
        f[ry][7] = bf2f((unsigned short)((unsigned)raw.w >> 16));
    }

    float acc[8];
#pragma unroll
    for (int j = 0; j < 8; j++) acc[j] = 0.f;

#pragma unroll
    for (int ry = 0; ry < 3; ry++) {
        float l = __shfl_up(f[ry][7], 1);
        float r = __shfl_down(f[ry][0], 1);
        if (wq == 0)  l = 0.f;
        if (wq == 15) r = 0.f;
        const float wl = wk[ry * 3 + 0], wc = wk[ry * 3 + 1], wr = wk[ry * 3 + 2];
        acc[0] = fmaf(wl, l, acc[0]);
#pragma unroll
        for (int j = 1; j < 8; j++) acc[j] = fmaf(wl, f[ry][j - 1], acc[j]);
#pragma unroll
        for (int j = 0; j < 8; j++) acc[j] = fmaf(wc, f[ry][j], acc[j]);
#pragma unroll
        for (int j = 0; j < 7; j++) acc[j] = fmaf(wr, f[ry][j + 1], acc[j]);
        acc[7] = fmaf(wr, r, acc[7]);
    }

    ushort4 o[2];
    unsigned short* po = (unsigned short*)o;
#pragma unroll
    for (int j = 0; j < 8; j++) po[j] = f2bf(acc[j]);
    *(int4*)(Zbf + ((long)z * C3 + oc) * N_PIX + p0) = *(const int4*)o;
}

// K3a: partial Gram G[24,24] + row sum-of-squares, bf16 input, fp32 math
__global__ __launch_bounds__(64) void gram_partial(const unsigned short* __restrict__ Zbf,
                                                   float* __restrict__ gpart) {
    const int split = blockIdx.x;
    const int bh    = blockIdx.y;
    const int which = blockIdx.z;
    const int b = bh >> 3, head = bh & 7;
    const int zq = (which == 0) ? b : 8 + b;
    const int zk = (which == 0) ? 8 + b : b;
    const unsigned short* Q  = Zbf + ((long)zq * C3 + head * HD) * N_PIX;
    const unsigned short* Kr = Zbf + ((long)zk * C3 + CC + head * HD) * N_PIX;

    __shared__ float Qc[24][132];
    __shared__ float Kc[24][132];

    const int t = threadIdx.x;
    const int ci = t >> 3, di = t & 7;
    const int c0 = ci * 3, d0 = di * 3;

    float acc[3][3];
#pragma unroll
    for (int i = 0; i < 3; i++)
#pragma unroll
        for (int j = 0; j < 3; j++) acc[i][j] = 0.f;
    float ss = 0.f;

    const int n0base = split * 2048;
    for (int nc = 0; nc < 2048; nc += 128) {
        const long n0 = n0base + nc;
        const unsigned short* src = nullptr;
        float* dstrow = nullptr;
        if (t < 24)               { src = Q  + (long)t * N_PIX + n0;        dstrow = Qc[t]; }
        else if (t >= 32 && t < 56) { src = Kr + (long)(t - 32) * N_PIX + n0; dstrow = Kc[t - 32]; }
        if (src) {
#pragma unroll 4
            for (int i = 0; i < 16; i++) {
                int4 raw = *(const int4*)(src + i * 8);
                float f[8];
                f[0] = bf2f((unsigned short)(raw.x & 0xffff)); f[1] = bf2f((unsigned short)((unsigned)raw.x >> 16));
                f[2] = bf2f((unsigned short)(raw.y & 0xffff)); f[3] = bf2f((unsigned short)((unsigned)raw.y >> 16));
                f[4] = bf2f((unsigned short)(raw.z & 0xffff)); f[5] = bf2f((unsigned short)((unsigned)raw.z >> 16));
                f[6] = bf2f((unsigned short)(raw.w & 0xffff)); f[7] = bf2f((unsigned short)((unsigned)raw.w >> 16));
                *(float4*)&dstrow[i * 8]     = make_float4(f[0], f[1], f[2], f[3]);
                *(float4*)&dstrow[i * 8 + 4] = make_float4(f[4], f[5], f[6], f[7]);
#pragma unroll
                for (int q = 0; q < 8; q++) ss = fmaf(f[q], f[q], ss);
            }
        }
        __syncthreads();
#pragma unroll 4
        for (int kk = 0; kk < 128; kk += 4) {
            float4 qv[3], kv[3];
#pragma unroll
            for (int i = 0; i < 3; i++) qv[i] = *(const float4*)&Qc[c0 + i][kk];
#pragma unroll
            for (int j = 0; j < 3; j++) kv[j] = *(const float4*)&Kc[d0 + j][kk];
#pragma unroll
            for (int i = 0; i < 3; i++)
#pragma unroll
                for (int j = 0; j < 3; j++)
                    acc[i][j] += qv[i].x * kv[j].x + qv[i].y * kv[j].y +
                                 qv[i].z * kv[j].z + qv[i].w * kv[j].w;
        }
        __syncthreads();
    }

    const int g = (which * 64 + bh) * 8 + split;
    float* gp = gpart + (long)g * 624;
#pragma unroll
    for (int i = 0; i < 3; i++)
#pragma unroll
        for (int j = 0; j < 3; j++)
            gp[(c0 + i) * 24 + (d0 + j)] = acc[i][j];
    if (t < 24) gp[576 + t] = ss;
    else if (t >= 32 && t < 56) gp[600 + (t - 32)] = ss;
}

// K3b: reduce splits, normalize, temperature, softmax -> P fp32
__global__ __launch_bounds__(256) void gram_reduce_softmax(const float* __restrict__ gpart,
                                                           const float* __restrict__ temperature,
                                                           float* __restrict__ P) {
    const int g = blockIdx.x;           // which*64 + b*8 + head
    const int head = g & 7;
    __shared__ float Gs[576];
    __shared__ float qs[24], ks[24], invq[24], invk[24];

    const int t = threadIdx.x;
    for (int e = t; e < 624; e += 256) {
        float s = 0.f;
        for (int sp = 0; sp < 8; sp++) s += gpart[(long)(g * 8 + sp) * 624 + e];
        if (e < 576) Gs[e] = s;
        else if (e < 600) qs[e - 576] = s;
        else ks[e - 600] = s;
    }
    __syncthreads();
    if (t < 24) {
        invq[t] = 1.f / fmaxf(sqrtf(qs[t]), 1e-12f);
        invk[t] = 1.f / fmaxf(sqrtf(ks[t]), 1e-12f);
    }
    __syncthreads();
    if (t < 24) {
        const float temp = temperature[head];
        float row[24];
        float m = -1e30f;
#pragma unroll
        for (int d = 0; d < 24; d++) {
            row[d] = Gs[t * 24 + d] * invq[t] * invk[d] * temp;
            m = fmaxf(m, row[d]);
        }
        float ssum = 0.f;
#pragma unroll
        for (int d = 0; d < 24; d++) {
            row[d] = expf(row[d] - m);
            ssum += row[d];
        }
        const float inv = 1.f / ssum;
#pragma unroll
        for (int d = 0; d < 24; d++)
            P[(long)g * 576 + t * 24 + d] = row[d] * inv;
    }
}

// K4: weff_bf[o][b] = wproj @ blockdiag(P[1-o][b])  (bf16 out)
__global__ __launch_bounds__(256) void build_weff(const float* __restrict__ wproj,
                                                  const float* __restrict__ P,
                                                  unsigned short* __restrict__ weff) {
    const int o = blockIdx.z, b = blockIdx.y;
    const int e = blockIdx.x * 256 + threadIdx.x;   // 0..36863
    const int co = e / 192, col = e % 192;
    const int head = col / 24, d = col % 24;
    const int which = 1 - o;
    const float* Pp = P + (long)(which * 64 + b * 8 + head) * 576;
    const float* wp = wproj + co * 192 + head * 24;
    float acc = 0.f;
#pragma unroll
    for (int hc = 0; hc < 24; hc++)
        acc = fmaf(wp[hc], Pp[hc * 24 + d], acc);
    weff[((long)(o * 8 + b) * 192 + co) * 192 + col] = f2bf(acc);
}

extern "C" void kernel_launch(void* const* d_in, const int* in_sizes, int n_in,
                              void* d_out, int out_size, void* d_ws, size_t ws_size,
                              hipStream_t stream) {
    (void)in_sizes; (void)n_in; (void)out_size; (void)ws_size;
    const float* rgb    = (const float*)d_in[0];
    const float* ir     = (const float*)d_in[1];
    const float* w_qkv  = (const float*)d_in[2];
    const float* w_dw   = (const float*)d_in[3];
    const float* w_proj = (const float*)d_in[4];
    const float* temp   = (const float*)d_in[5];
    float* out = (float*)d_out;

    char* wsb = (char*)d_ws;
    unsigned short* Y_bf    = (unsigned short*)(wsb);                 // 301,989,888 B
    unsigned short* Z_bf    = (unsigned short*)(wsb + 301989888L);    // 301,989,888 B
    unsigned short* w_bf    = (unsigned short*)(wsb + 603979776L);    //     221,184 B
    unsigned short* weff_bf = (unsigned short*)(wsb + 604200960L);    //   1,179,648 B
    float*          gpart   = (float*)(wsb + 605380608L);             //   2,555,904 B
    float*          P       = (float*)(wsb + 607936512L);             //     294,912 B

    cvt_f32_bf16<<<108, 256, 0, stream>>>(w_qkv, w_bf, 27648);
    qkv_mfma<<<dim3(128, 3, 16), 256, 0, stream>>>(w_bf, rgb, ir, Y_bf);
    dwconv3x3<<<dim3(8, 576, 16), 256, 0, stream>>>(Y_bf, w_dw, Z_bf);
    gram_partial<<<dim3(8, 64, 2), 64, 0, stream>>>(Z_bf, gpart);
    gram_reduce_softmax<<<128, 256, 0, stream>>>(gpart, temp, P);
    build_weff<<<dim3(144, 8, 2), 256, 0, stream>>>(w_proj, P, weff_bf);
    out_mfma<<<dim3(128, 1, 16), 256, 0, stream>>>(weff_bf, Z_bf, out);
}

// Round 3
// 807.547 us; speedup vs baseline: 1.1056x; 1.1056x over previous
//
#include <hip/hip_runtime.h>

#define N_PIX 16384   // 128*128
#define CC    192
#define C3    576
#define KK    192     // GEMM K (=CC)
#define HD    24

typedef __attribute__((ext_vector_type(8))) short short8;   // 8 bf16 = 4 VGPR
typedef __attribute__((ext_vector_type(4))) float f32x4;    // MFMA acc

__device__ __forceinline__ unsigned short f2bf(float x) {
    unsigned u = __float_as_uint(x);
    u += 0x7fff + ((u >> 16) & 1);          // round-to-nearest-even
    return (unsigned short)(u >> 16);
}
__device__ __forceinline__ float bf2f(unsigned short s) {
    return __uint_as_float(((unsigned)s) << 16);
}
__device__ __forceinline__ int pack2(unsigned short lo, unsigned short hi) {
    return (int)(((unsigned)hi << 16) | (unsigned)lo);
}

// K0: fp32 -> bf16 bulk convert (vector of 4)
__global__ __launch_bounds__(256) void cvt_f32_bf16(const float* __restrict__ src,
                                                    unsigned short* __restrict__ dst, int n4) {
    int i = blockIdx.x * 256 + threadIdx.x;
    if (i < n4) {
        float4 v = ((const float4*)src)[i];
        ushort4 o;
        o.x = f2bf(v.x); o.y = f2bf(v.y); o.z = f2bf(v.z); o.w = f2bf(v.w);
        ((ushort4*)dst)[i] = o;
    }
}

// ---------------------------------------------------------------------------
// bf16 MFMA GEMM body: C[m0+192, n0+128] = A[*,192] @ B[192, N_PIX]
// v4: 512 threads = 8 waves (2x4), wave tile 96x32 -> acc[6][2] = 48 regs/lane.
//     __launch_bounds__(512,4): 4 waves/SIMD (16 waves/CU) for latency hiding.
//     Single-buffered LDS (round-1 structure; reg-prefetch spilled in v3).
//     Pad +12 (88B row stride): frag reads conflict-free, writes ~2-way.
// A: bf16 row-major [M][192]. B: fp32 or bf16 [192][N_PIX]. C: bf16 or fp32.
// ---------------------------------------------------------------------------
template<bool B_F32, bool C_BF16>
__device__ __forceinline__ void mfma_gemm(const unsigned short* __restrict__ Abf,
                                          const void* __restrict__ Bsrc,
                                          void* __restrict__ Cdst,
                                          int m0, int n0) {
    __shared__ unsigned short As[192][44];   // [m][k]
    __shared__ unsigned short Bs[128][44];   // [n][k]

    const int tid  = threadIdx.x;
    const int wave = tid >> 6, lane = tid & 63;
    const int quad = lane >> 4, l15 = lane & 15;
    const int wr = wave >> 2, wc = wave & 3;   // 2 x 4 wave grid

    f32x4 acc[6][2];
#pragma unroll
    for (int i = 0; i < 6; i++)
#pragma unroll
        for (int j = 0; j < 2; j++) acc[i][j] = (f32x4)0.f;

    const int kg = tid & 7;        // B staging: k-group of 4 (kg*4)
    const int n2 = tid >> 3;       // B staging: col-pair (n2*2), 0..63

    for (int k0 = 0; k0 < KK; k0 += 32) {
        // ---- stage A: 192x32 bf16 = 768 int4 chunks over 512 threads ----
        {
            int row = tid >> 2, kc = (tid & 3) * 8;
            *(int4*)&As[row][kc] = *(const int4*)(Abf + (long)(m0 + row) * KK + k0 + kc);
            if (tid < 256) {
                int ch = tid + 512;
                int row2 = ch >> 2, kc2 = (ch & 3) * 8;
                *(int4*)&As[row2][kc2] = *(const int4*)(Abf + (long)(m0 + row2) * KK + k0 + kc2);
            }
        }
        // ---- stage B: 32x128, transpose to [n][k], cvt if fp32 ----
        if (B_F32) {
            const float* Bp = (const float*)Bsrc;
            float2 v[4];
#pragma unroll
            for (int j = 0; j < 4; j++)
                v[j] = *(const float2*)(Bp + (long)(k0 + kg * 4 + j) * N_PIX + n0 + n2 * 2);
#pragma unroll
            for (int i = 0; i < 2; i++) {
                unsigned short us[4];
#pragma unroll
                for (int j = 0; j < 4; j++) us[j] = f2bf(i ? v[j].y : v[j].x);
                int2 pk = make_int2(pack2(us[0], us[1]), pack2(us[2], us[3]));
                *(int2*)&Bs[n2 * 2 + i][kg * 4] = pk;
            }
        } else {
            const unsigned short* Bp = (const unsigned short*)Bsrc;
            ushort2 v[4];
#pragma unroll
            for (int j = 0; j < 4; j++)
                v[j] = *(const ushort2*)(Bp + (long)(k0 + kg * 4 + j) * N_PIX + n0 + n2 * 2);
#pragma unroll
            for (int i = 0; i < 2; i++) {
                unsigned short us[4];
#pragma unroll
                for (int j = 0; j < 4; j++) us[j] = i ? v[j].y : v[j].x;
                int2 pk = make_int2(pack2(us[0], us[1]), pack2(us[2], us[3]));
                *(int2*)&Bs[n2 * 2 + i][kg * 4] = pk;
            }
        }
        __syncthreads();

        short8 a[6], b[2];
#pragma unroll
        for (int mi = 0; mi < 6; mi++)
            a[mi] = *(const short8*)&As[wr * 96 + mi * 16 + l15][quad * 8];
#pragma unroll
        for (int ni = 0; ni < 2; ni++)
            b[ni] = *(const short8*)&Bs[wc * 32 + ni * 16 + l15][quad * 8];
#pragma unroll
        for (int mi = 0; mi < 6; mi++)
#pragma unroll
            for (int ni = 0; ni < 2; ni++)
                acc[mi][ni] = __builtin_amdgcn_mfma_f32_16x16x32_bf16(a[mi], b[ni], acc[mi][ni], 0, 0, 0);
        __syncthreads();
    }

    // ---- epilogue: C/D layout col=lane&15, row=quad*4+reg ----
#pragma unroll
    for (int mi = 0; mi < 6; mi++)
#pragma unroll
        for (int ni = 0; ni < 2; ni++)
#pragma unroll
            for (int r = 0; r < 4; r++) {
                int row = m0 + wr * 96 + mi * 16 + quad * 4 + r;
                int col = n0 + wc * 32 + ni * 16 + l15;
                if (C_BF16)
                    ((unsigned short*)Cdst)[(long)row * N_PIX + col] = f2bf(acc[mi][ni][r]);
                else
                    ((float*)Cdst)[(long)row * N_PIX + col] = acc[mi][ni][r];
            }
}

// K1: Y[z][576,N] = w_bf[576,192] @ x[z][192,N]   (z = mod*8+b), bf16 out
__global__ __launch_bounds__(512, 4) void qkv_mfma(const unsigned short* __restrict__ wbf,
                                                   const float* __restrict__ rgb,
                                                   const float* __restrict__ ir,
                                                   unsigned short* __restrict__ Ybf) {
    const int z = blockIdx.z, mod = z >> 3, b = z & 7;
    const float* x = (mod ? ir : rgb) + (long)b * CC * N_PIX;
    unsigned short* y = Ybf + (long)z * C3 * N_PIX;
    mfma_gemm<true, true>(wbf, x, y, blockIdx.y * 192, blockIdx.x * 128);
}

// K5: out[z][192,N] = weff_bf[z][192,192] @ V[z][192,N], fp32 out
__global__ __launch_bounds__(512, 4) void out_mfma(const unsigned short* __restrict__ weff,
                                                   const unsigned short* __restrict__ Zbf,
                                                   float* __restrict__ out) {
    const int z = blockIdx.z;   // o*8+b; V modality == o
    const unsigned short* V = Zbf + ((long)z * C3 + 2 * CC) * N_PIX;
    float* C = out + (long)z * CC * N_PIX;
    mfma_gemm<false, false>(weff + (long)z * CC * CC, V, C, 0, blockIdx.x * 128);
}

// K2 v2: depthwise 3x3 SAME, bf16 in/out, 8 px/thread, vector loads + lane shuffles.
__global__ __launch_bounds__(256) void dwconv3x3(const unsigned short* __restrict__ Ybf,
                                                 const float* __restrict__ wdw,
                                                 unsigned short* __restrict__ Zbf) {
    const int z  = blockIdx.z;
    const int oc = blockIdx.y;
    const int idx = blockIdx.x * 256 + threadIdx.x;   // 0..2047
    const int p0  = idx * 8;
    const int h   = p0 >> 7;
    const int w0  = p0 & 127;
    const int wq  = threadIdx.x & 15;                 // == w0/8
    const unsigned short* Yc = Ybf + ((long)z * C3 + oc) * N_PIX;

    float wk[9];
#pragma unroll
    for (int i = 0; i < 9; i++) wk[i] = wdw[oc * 9 + i];

    float f[3][8];
#pragma unroll
    for (int ry = 0; ry < 3; ry++) {
        const int hy = h + ry - 1;
        int4 raw = make_int4(0, 0, 0, 0);
        if (hy >= 0 && hy <= 127)
            raw = *(const int4*)(Yc + hy * 128 + w0);
        f[ry][0] = bf2f((unsigned short)(raw.x & 0xffff));
        f[ry][1] = bf2f((unsigned short)((unsigned)raw.x >> 16));
        f[ry][2] = bf2f((unsigned short)(raw.y & 0xffff));
        f[ry][3] = bf2f((unsigned short)((unsigned)raw.y >> 16));
        f[ry][4] = bf2f((unsigned short)(raw.z & 0xffff));
        f[ry][5] = bf2f((unsigned short)((unsigned)raw.z >> 16));
        f[ry][6] = bf2f((unsigned short)(raw.w & 0xffff));
        f[ry][7] = bf2f((unsigned short)((unsigned)raw.w >> 16));
    }

    float acc[8];
#pragma unroll
    for (int j = 0; j < 8; j++) acc[j] = 0.f;

#pragma unroll
    for (int ry = 0; ry < 3; ry++) {
        float l = __shfl_up(f[ry][7], 1);
        float r = __shfl_down(f[ry][0], 1);
        if (wq == 0)  l = 0.f;
        if (wq == 15) r = 0.f;
        const float wl = wk[ry * 3 + 0], wc = wk[ry * 3 + 1], wr = wk[ry * 3 + 2];
        acc[0] = fmaf(wl, l, acc[0]);
#pragma unroll
        for (int j = 1; j < 8; j++) acc[j] = fmaf(wl, f[ry][j - 1], acc[j]);
#pragma unroll
        for (int j = 0; j < 8; j++) acc[j] = fmaf(wc, f[ry][j], acc[j]);
#pragma unroll
        for (int j = 0; j < 7; j++) acc[j] = fmaf(wr, f[ry][j + 1], acc[j]);
        acc[7] = fmaf(wr, r, acc[7]);
    }

    ushort4 o[2];
    unsigned short* po = (unsigned short*)o;
#pragma unroll
    for (int j = 0; j < 8; j++) po[j] = f2bf(acc[j]);
    *(int4*)(Zbf + ((long)z * C3 + oc) * N_PIX + p0) = *(const int4*)o;
}

// K3a: partial Gram G[24,24] + row sum-of-squares, bf16 input, fp32 math
__global__ __launch_bounds__(64) void gram_partial(const unsigned short* __restrict__ Zbf,
                                                   float* __restrict__ gpart) {
    const int split = blockIdx.x;
    const int bh    = blockIdx.y;
    const int which = blockIdx.z;
    const int b = bh >> 3, head = bh & 7;
    const int zq = (which == 0) ? b : 8 + b;
    const int zk = (which == 0) ? 8 + b : b;
    const unsigned short* Q  = Zbf + ((long)zq * C3 + head * HD) * N_PIX;
    const unsigned short* Kr = Zbf + ((long)zk * C3 + CC + head * HD) * N_PIX;

    __shared__ float Qc[24][132];
    __shared__ float Kc[24][132];

    const int t = threadIdx.x;
    const int ci = t >> 3, di = t & 7;
    const int c0 = ci * 3, d0 = di * 3;

    float acc[3][3];
#pragma unroll
    for (int i = 0; i < 3; i++)
#pragma unroll
        for (int j = 0; j < 3; j++) acc[i][j] = 0.f;
    float ss = 0.f;

    const int n0base = split * 2048;
    for (int nc = 0; nc < 2048; nc += 128) {
        const long n0 = n0base + nc;
        const unsigned short* src = nullptr;
        float* dstrow = nullptr;
        if (t < 24)               { src = Q  + (long)t * N_PIX + n0;        dstrow = Qc[t]; }
        else if (t >= 32 && t < 56) { src = Kr + (long)(t - 32) * N_PIX + n0; dstrow = Kc[t - 32]; }
        if (src) {
#pragma unroll 4
            for (int i = 0; i < 16; i++) {
                int4 raw = *(const int4*)(src + i * 8);
                float f[8];
                f[0] = bf2f((unsigned short)(raw.x & 0xffff)); f[1] = bf2f((unsigned short)((unsigned)raw.x >> 16));
                f[2] = bf2f((unsigned short)(raw.y & 0xffff)); f[3] = bf2f((unsigned short)((unsigned)raw.y >> 16));
                f[4] = bf2f((unsigned short)(raw.z & 0xffff)); f[5] = bf2f((unsigned short)((unsigned)raw.z >> 16));
                f[6] = bf2f((unsigned short)(raw.w & 0xffff)); f[7] = bf2f((unsigned short)((unsigned)raw.w >> 16));
                *(float4*)&dstrow[i * 8]     = make_float4(f[0], f[1], f[2], f[3]);
                *(float4*)&dstrow[i * 8 + 4] = make_float4(f[4], f[5], f[6], f[7]);
#pragma unroll
                for (int q = 0; q < 8; q++) ss = fmaf(f[q], f[q], ss);
            }
        }
        __syncthreads();
#pragma unroll 4
        for (int kk = 0; kk < 128; kk += 4) {
            float4 qv[3], kv[3];
#pragma unroll
            for (int i = 0; i < 3; i++) qv[i] = *(const float4*)&Qc[c0 + i][kk];
#pragma unroll
            for (int j = 0; j < 3; j++) kv[j] = *(const float4*)&Kc[d0 + j][kk];
#pragma unroll
            for (int i = 0; i < 3; i++)
#pragma unroll
                for (int j = 0; j < 3; j++)
                    acc[i][j] += qv[i].x * kv[j].x + qv[i].y * kv[j].y +
                                 qv[i].z * kv[j].z + qv[i].w * kv[j].w;
        }
        __syncthreads();
    }

    const int g = (which * 64 + bh) * 8 + split;
    float* gp = gpart + (long)g * 624;
#pragma unroll
    for (int i = 0; i < 3; i++)
#pragma unroll
        for (int j = 0; j < 3; j++)
            gp[(c0 + i) * 24 + (d0 + j)] = acc[i][j];
    if (t < 24) gp[576 + t] = ss;
    else if (t >= 32 && t < 56) gp[600 + (t - 32)] = ss;
}

// K3b: reduce splits, normalize, temperature, softmax -> P fp32
__global__ __launch_bounds__(256) void gram_reduce_softmax(const float* __restrict__ gpart,
                                                           const float* __restrict__ temperature,
                                                           float* __restrict__ P) {
    const int g = blockIdx.x;           // which*64 + b*8 + head
    const int head = g & 7;
    __shared__ float Gs[576];
    __shared__ float qs[24], ks[24], invq[24], invk[24];

    const int t = threadIdx.x;
    for (int e = t; e < 624; e += 256) {
        float s = 0.f;
        for (int sp = 0; sp < 8; sp++) s += gpart[(long)(g * 8 + sp) * 624 + e];
        if (e < 576) Gs[e] = s;
        else if (e < 600) qs[e - 576] = s;
        else ks[e - 600] = s;
    }
    __syncthreads();
    if (t < 24) {
        invq[t] = 1.f / fmaxf(sqrtf(qs[t]), 1e-12f);
        invk[t] = 1.f / fmaxf(sqrtf(ks[t]), 1e-12f);
    }
    __syncthreads();
    if (t < 24) {
        const float temp = temperature[head];
        float row[24];
        float m = -1e30f;
#pragma unroll
        for (int d = 0; d < 24; d++) {
            row[d] = Gs[t * 24 + d] * invq[t] * invk[d] * temp;
            m = fmaxf(m, row[d]);
        }
        float ssum = 0.f;
#pragma unroll
        for (int d = 0; d < 24; d++) {
            row[d] = expf(row[d] - m);
            ssum += row[d];
        }
        const float inv = 1.f / ssum;
#pragma unroll
        for (int d = 0; d < 24; d++)
            P[(long)g * 576 + t * 24 + d] = row[d] * inv;
    }
}

// K4: weff_bf[o][b] = wproj @ blockdiag(P[1-o][b])  (bf16 out)
__global__ __launch_bounds__(256) void build_weff(const float* __restrict__ wproj,
                                                  const float* __restrict__ P,
                                                  unsigned short* __restrict__ weff) {
    const int o = blockIdx.z, b = blockIdx.y;
    const int e = blockIdx.x * 256 + threadIdx.x;   // 0..36863
    const int co = e / 192, col = e % 192;
    const int head = col / 24, d = col % 24;
    const int which = 1 - o;
    const float* Pp = P + (long)(which * 64 + b * 8 + head) * 576;
    const float* wp = wproj + co * 192 + head * 24;
    float acc = 0.f;
#pragma unroll
    for (int hc = 0; hc < 24; hc++)
        acc = fmaf(wp[hc], Pp[hc * 24 + d], acc);
    weff[((long)(o * 8 + b) * 192 + co) * 192 + col] = f2bf(acc);
}

extern "C" void kernel_launch(void* const* d_in, const int* in_sizes, int n_in,
                              void* d_out, int out_size, void* d_ws, size_t ws_size,
                              hipStream_t stream) {
    (void)in_sizes; (void)n_in; (void)out_size; (void)ws_size;
    const float* rgb    = (const float*)d_in[0];
    const float* ir     = (const float*)d_in[1];
    const float* w_qkv  = (const float*)d_in[2];
    const float* w_dw   = (const float*)d_in[3];
    const float* w_proj = (const float*)d_in[4];
    const float* temp   = (const float*)d_in[5];
    float* out = (float*)d_out;

    char* wsb = (char*)d_ws;
    unsigned short* Y_bf    = (unsigned short*)(wsb);                 // 301,989,888 B
    unsigned short* Z_bf    = (unsigned short*)(wsb + 301989888L);    // 301,989,888 B
    unsigned short* w_bf    = (unsigned short*)(wsb + 603979776L);    //     221,184 B
    unsigned short* weff_bf = (unsigned short*)(wsb + 604200960L);    //   1,179,648 B
    float*          gpart   = (float*)(wsb + 605380608L);             //   2,555,904 B
    float*          P       = (float*)(wsb + 607936512L);             //     294,912 B

    cvt_f32_bf16<<<108, 256, 0, stream>>>(w_qkv, w_bf, 27648);
    qkv_mfma<<<dim3(128, 3, 16), 512, 0, stream>>>(w_bf, rgb, ir, Y_bf);
    dwconv3x3<<<dim3(8, 576, 16), 256, 0, stream>>>(Y_bf, w_dw, Z_bf);
    gram_partial<<<dim3(8, 64, 2), 64, 0, stream>>>(Z_bf, gpart);
    gram_reduce_softmax<<<128, 256, 0, stream>>>(gpart, temp, P);
    build_weff<<<dim3(144, 8, 2), 256, 0, stream>>>(w_proj, P, weff_bf);
    out_mfma<<<dim3(128, 1, 16), 512, 0, stream>>>(weff_bf, Z_bf, out);
}

// Round 4
// 799.398 us; speedup vs baseline: 1.1169x; 1.0102x over previous
//
#include <hip/hip_runtime.h>

#define N_PIX 16384   // 128*128
#define CC    192
#define C3    576
#define KK    192     // GEMM K (=CC)
#define HD    24
#define KS    64      // qkv v5 K-step

typedef __attribute__((ext_vector_type(8))) short short8;   // 8 bf16 = 4 VGPR
typedef __attribute__((ext_vector_type(4))) float f32x4;    // MFMA acc

__device__ __forceinline__ unsigned short f2bf(float x) {
    unsigned u = __float_as_uint(x);
    u += 0x7fff + ((u >> 16) & 1);          // round-to-nearest-even
    return (unsigned short)(u >> 16);
}
__device__ __forceinline__ float bf2f(unsigned short s) {
    return __uint_as_float(((unsigned)s) << 16);
}
__device__ __forceinline__ int pack2(unsigned short lo, unsigned short hi) {
    return (int)(((unsigned)hi << 16) | (unsigned)lo);
}

// async global->LDS, 16B per lane; lds dest is wave-uniform base + lane*16
__device__ __forceinline__ void g2l16(const unsigned short* g, unsigned short* l) {
    __builtin_amdgcn_global_load_lds(
        (const __attribute__((address_space(1))) void*)g,
        (__attribute__((address_space(3))) void*)l, 16, 0, 0);
}

// K0: fp32 -> bf16 bulk convert (vector of 4)
__global__ __launch_bounds__(256) void cvt_f32_bf16(const float* __restrict__ src,
                                                    unsigned short* __restrict__ dst, int n4) {
    int i = blockIdx.x * 256 + threadIdx.x;
    if (i < n4) {
        float4 v = ((const float4*)src)[i];
        ushort4 o;
        o.x = f2bf(v.x); o.y = f2bf(v.y); o.z = f2bf(v.z); o.w = f2bf(v.w);
        ((ushort4*)dst)[i] = o;
    }
}

// K0b: transpose+convert x[z][192][16384] fp32 -> xT[z][16384][192] bf16.
// Per block: one z, 128 pixels, all 192 channels. Coalesced both sides via LDS.
__global__ __launch_bounds__(256) void cvtT(const float* __restrict__ rgb,
                                            const float* __restrict__ ir,
                                            unsigned short* __restrict__ xT) {
    const int z  = blockIdx.y;
    const int n0 = blockIdx.x * 128;
    const float* x = ((z >= 8) ? ir : rgb) + (long)(z & 7) * CC * N_PIX;
    __shared__ unsigned short T[192][136];   // row 272B; b64 writes 2-way (free)

    const int t = threadIdx.x;
    // load: 192 rows x 32 float4 = 6144 chunks
#pragma unroll
    for (int i = 0; i < 24; i++) {
        int q = i * 256 + t;
        int k = q >> 5, nc = q & 31;
        float4 v = *(const float4*)(x + (long)k * N_PIX + n0 + nc * 4);
        ushort4 o;
        o.x = f2bf(v.x); o.y = f2bf(v.y); o.z = f2bf(v.z); o.w = f2bf(v.w);
        *(ushort4*)&T[k][nc * 4] = o;
    }
    __syncthreads();
    // store: 128 n-rows x 24 16B-chunks = 3072 chunks, fully linear in xT
    unsigned short* dst = xT + ((long)z * N_PIX + n0) * CC;
#pragma unroll
    for (int i = 0; i < 12; i++) {
        int c = i * 256 + t;
        int n = c / 24, kc = c - n * 24;
        unsigned short us[8];
#pragma unroll
        for (int j = 0; j < 8; j++) us[j] = T[kc * 8 + j][n];
        int4 pk = make_int4(pack2(us[0], us[1]), pack2(us[2], us[3]),
                            pack2(us[4], us[5]), pack2(us[6], us[7]));
        *(int4*)(dst + (long)n * CC + kc * 8) = pk;
    }
}

// ---------------------------------------------------------------------------
// qkv v5: Y[z][576,16384] = w_bf[576,192] @ xT[z][16384,192]^T
// 512 thr = 8 waves (2x4), wave tile 96x32, acc[6][2]. K-step 64, 3 iters.
// Double-buffered LDS, global_load_lds staging (no staging registers).
// Chunk-XOR swizzle (c ^= row&7) applied on source AND read: 2-way banks=free.
// LDS = 2*(192+128)*128B = 163840 B total per... per block 81920 B -> 2 blk/CU.
// ---------------------------------------------------------------------------
__global__ __launch_bounds__(512, 4) void qkv_mfma(const unsigned short* __restrict__ wbf,
                                                   const unsigned short* __restrict__ xT,
                                                   unsigned short* __restrict__ Ybf) {
    const int z  = blockIdx.z;
    const unsigned short* Bg = xT + (long)z * N_PIX * CC;   // [n][k] bf16
    unsigned short* y = Ybf + (long)z * C3 * N_PIX;
    const int m0 = blockIdx.y * 192, n0 = blockIdx.x * 128;

    __shared__ unsigned short As[2][192 * 64];   // chunk (m*8+c), row 128B
    __shared__ unsigned short Bs[2][128 * 64];

    const int tid  = threadIdx.x;
    const int wave = tid >> 6, lane = tid & 63;
    const int quad = lane >> 4, l15 = lane & 15;
    const int wr = wave >> 2, wc = wave & 3;   // 2 x 4 wave grid

    f32x4 acc[6][2];
#pragma unroll
    for (int i = 0; i < 6; i++)
#pragma unroll
        for (int j = 0; j < 2; j++) acc[i][j] = (f32x4)0.f;

    // ---- stage one K-step (A: 1536 chunks = 3 instr/wave, B: 1024 = 2) ----
    auto stage = [&](int buf, int k0) {
#pragma unroll
        for (int s = 0; s < 3; s++) {
            int j = s * 8 + wave;
            int q = j * 64 + lane;
            int m = q >> 3, c = (q & 7) ^ (m & 7);
            g2l16(wbf + (long)(m0 + m) * KK + k0 + c * 8, &As[buf][j * 512]);
        }
#pragma unroll
        for (int s = 0; s < 2; s++) {
            int j = s * 8 + wave;
            int q = j * 64 + lane;
            int n = q >> 3, c = (q & 7) ^ (n & 7);
            g2l16(Bg + (long)(n0 + n) * CC + k0 + c * 8, &Bs[buf][j * 512]);
        }
    };

    stage(0, 0);
    __syncthreads();                 // compiler drains vmcnt(0) before barrier
    int cur = 0;
    for (int it = 0; it < 3; ++it) {
        if (it < 2) stage(cur ^ 1, (it + 1) * KS);   // async loads in flight
        const unsigned short* A  = As[cur];
        const unsigned short* Bl = Bs[cur];
#pragma unroll
        for (int kk = 0; kk < 2; kk++) {
            short8 a[6], b[2];
#pragma unroll
            for (int mi = 0; mi < 6; mi++) {
                int r = wr * 96 + mi * 16 + l15;
                int c = (kk * 4 + quad) ^ (r & 7);
                a[mi] = *(const short8*)&A[r * 64 + c * 8];
            }
#pragma unroll
            for (int ni = 0; ni < 2; ni++) {
                int n = wc * 32 + ni * 16 + l15;
                int c = (kk * 4 + quad) ^ (n & 7);
                b[ni] = *(const short8*)&Bl[n * 64 + c * 8];
            }
#pragma unroll
            for (int mi = 0; mi < 6; mi++)
#pragma unroll
                for (int ni = 0; ni < 2; ni++)
                    acc[mi][ni] = __builtin_amdgcn_mfma_f32_16x16x32_bf16(a[mi], b[ni], acc[mi][ni], 0, 0, 0);
        }
        __syncthreads();             // drains this iter's stage; protects cur
        cur ^= 1;
    }

    // ---- epilogue: C/D layout col=lane&15, row=quad*4+reg ----
#pragma unroll
    for (int mi = 0; mi < 6; mi++)
#pragma unroll
        for (int ni = 0; ni < 2; ni++)
#pragma unroll
            for (int r = 0; r < 4; r++) {
                int row = m0 + wr * 96 + mi * 16 + quad * 4 + r;
                int col = n0 + wc * 32 + ni * 16 + l15;
                y[(long)row * N_PIX + col] = f2bf(acc[mi][ni][r]);
            }
}

// ---------------------------------------------------------------------------
// old GEMM body (round-3 structure) — still used by out_mfma this round.
// ---------------------------------------------------------------------------
__device__ __forceinline__ void mfma_gemm_old(const unsigned short* __restrict__ Abf,
                                              const unsigned short* __restrict__ Bsrc,
                                              float* __restrict__ Cdst,
                                              int m0, int n0) {
    __shared__ unsigned short As[192][44];   // [m][k]
    __shared__ unsigned short Bs[128][44];   // [n][k]

    const int tid  = threadIdx.x;
    const int wave = tid >> 6, lane = tid & 63;
    const int quad = lane >> 4, l15 = lane & 15;
    const int wr = wave >> 2, wc = wave & 3;   // 2 x 4 wave grid

    f32x4 acc[6][2];
#pragma unroll
    for (int i = 0; i < 6; i++)
#pragma unroll
        for (int j = 0; j < 2; j++) acc[i][j] = (f32x4)0.f;

    const int kg = tid & 7;        // B staging: k-group of 4 (kg*4)
    const int n2 = tid >> 3;       // B staging: col-pair (n2*2), 0..63

    for (int k0 = 0; k0 < KK; k0 += 32) {
        {
            int row = tid >> 2, kc = (tid & 3) * 8;
            *(int4*)&As[row][kc] = *(const int4*)(Abf + (long)(m0 + row) * KK + k0 + kc);
            if (tid < 256) {
                int ch = tid + 512;
                int row2 = ch >> 2, kc2 = (ch & 3) * 8;
                *(int4*)&As[row2][kc2] = *(const int4*)(Abf + (long)(m0 + row2) * KK + k0 + kc2);
            }
        }
        {
            ushort2 v[4];
#pragma unroll
            for (int j = 0; j < 4; j++)
                v[j] = *(const ushort2*)(Bsrc + (long)(k0 + kg * 4 + j) * N_PIX + n0 + n2 * 2);
#pragma unroll
            for (int i = 0; i < 2; i++) {
                unsigned short us[4];
#pragma unroll
                for (int j = 0; j < 4; j++) us[j] = i ? v[j].y : v[j].x;
                int2 pk = make_int2(pack2(us[0], us[1]), pack2(us[2], us[3]));
                *(int2*)&Bs[n2 * 2 + i][kg * 4] = pk;
            }
        }
        __syncthreads();

        short8 a[6], b[2];
#pragma unroll
        for (int mi = 0; mi < 6; mi++)
            a[mi] = *(const short8*)&As[wr * 96 + mi * 16 + l15][quad * 8];
#pragma unroll
        for (int ni = 0; ni < 2; ni++)
            b[ni] = *(const short8*)&Bs[wc * 32 + ni * 16 + l15][quad * 8];
#pragma unroll
        for (int mi = 0; mi < 6; mi++)
#pragma unroll
            for (int ni = 0; ni < 2; ni++)
                acc[mi][ni] = __builtin_amdgcn_mfma_f32_16x16x32_bf16(a[mi], b[ni], acc[mi][ni], 0, 0, 0);
        __syncthreads();
    }

#pragma unroll
    for (int mi = 0; mi < 6; mi++)
#pragma unroll
        for (int ni = 0; ni < 2; ni++)
#pragma unroll
            for (int r = 0; r < 4; r++) {
                int row = m0 + wr * 96 + mi * 16 + quad * 4 + r;
                int col = n0 + wc * 32 + ni * 16 + l15;
                Cdst[(long)row * N_PIX + col] = acc[mi][ni][r];
            }
}

// K5: out[z][192,N] = weff_bf[z][192,192] @ V[z][192,N], fp32 out
__global__ __launch_bounds__(512, 4) void out_mfma(const unsigned short* __restrict__ weff,
                                                   const unsigned short* __restrict__ Zbf,
                                                   float* __restrict__ out) {
    const int z = blockIdx.z;   // o*8+b; V modality == o
    const unsigned short* V = Zbf + ((long)z * C3 + 2 * CC) * N_PIX;
    float* C = out + (long)z * CC * N_PIX;
    mfma_gemm_old(weff + (long)z * CC * CC, V, C, 0, blockIdx.x * 128);
}

// K2 v2: depthwise 3x3 SAME, bf16 in/out, 8 px/thread, vector loads + lane shuffles.
__global__ __launch_bounds__(256) void dwconv3x3(const unsigned short* __restrict__ Ybf,
                                                 const float* __restrict__ wdw,
                                                 unsigned short* __restrict__ Zbf) {
    const int z  = blockIdx.z;
    const int oc = blockIdx.y;
    const int idx = blockIdx.x * 256 + threadIdx.x;   // 0..2047
    const int p0  = idx * 8;
    const int h   = p0 >> 7;
    const int w0  = p0 & 127;
    const int wq  = threadIdx.x & 15;                 // == w0/8
    const unsigned short* Yc = Ybf + ((long)z * C3 + oc) * N_PIX;

    float wk[9];
#pragma unroll
    for (int i = 0; i < 9; i++) wk[i] = wdw[oc * 9 + i];

    float f[3][8];
#pragma unroll
    for (int ry = 0; ry < 3; ry++) {
        const int hy = h + ry - 1;
        int4 raw = make_int4(0, 0, 0, 0);
        if (hy >= 0 && hy <= 127)
            raw = *(const int4*)(Yc + hy * 128 + w0);
        f[ry][0] = bf2f((unsigned short)(raw.x & 0xffff));
        f[ry][1] = bf2f((unsigned short)((unsigned)raw.x >> 16));
        f[ry][2] = bf2f((unsigned short)(raw.y & 0xffff));
        f[ry][3] = bf2f((unsigned short)((unsigned)raw.y >> 16));
        f[ry][4] = bf2f((unsigned short)(raw.z & 0xffff));
        f[ry][5] = bf2f((unsigned short)((unsigned)raw.z >> 16));
        f[ry][6] = bf2f((unsigned short)(raw.w & 0xffff));
        f[ry][7] = bf2f((unsigned short)((unsigned)raw.w >> 16));
    }

    float acc[8];
#pragma unroll
    for (int j = 0; j < 8; j++) acc[j] = 0.f;

#pragma unroll
    for (int ry = 0; ry < 3; ry++) {
        float l = __shfl_up(f[ry][7], 1);
        float r = __shfl_down(f[ry][0], 1);
        if (wq == 0)  l = 0.f;
        if (wq == 15) r = 0.f;
        const float wl = wk[ry * 3 + 0], wc = wk[ry * 3 + 1], wr = wk[ry * 3 + 2];
        acc[0] = fmaf(wl, l, acc[0]);
#pragma unroll
        for (int j = 1; j < 8; j++) acc[j] = fmaf(wl, f[ry][j - 1], acc[j]);
#pragma unroll
        for (int j = 0; j < 8; j++) acc[j] = fmaf(wc, f[ry][j], acc[j]);
#pragma unroll
        for (int j = 0; j < 7; j++) acc[j] = fmaf(wr, f[ry][j + 1], acc[j]);
        acc[7] = fmaf(wr, r, acc[7]);
    }

    ushort4 o[2];
    unsigned short* po = (unsigned short*)o;
#pragma unroll
    for (int j = 0; j < 8; j++) po[j] = f2bf(acc[j]);
    *(int4*)(Zbf + ((long)z * C3 + oc) * N_PIX + p0) = *(const int4*)o;
}

// K3a: partial Gram G[24,24] + row sum-of-squares, bf16 input, fp32 math
__global__ __launch_bounds__(64) void gram_partial(const unsigned short* __restrict__ Zbf,
                                                   float* __restrict__ gpart) {
    const int split = blockIdx.x;
    const int bh    = blockIdx.y;
    const int which = blockIdx.z;
    const int b = bh >> 3, head = bh & 7;
    const int zq = (which == 0) ? b : 8 + b;
    const int zk = (which == 0) ? 8 + b : b;
    const unsigned short* Q  = Zbf + ((long)zq * C3 + head * HD) * N_PIX;
    const unsigned short* Kr = Zbf + ((long)zk * C3 + CC + head * HD) * N_PIX;

    __shared__ float Qc[24][132];
    __shared__ float Kc[24][132];

    const int t = threadIdx.x;
    const int ci = t >> 3, di = t & 7;
    const int c0 = ci * 3, d0 = di * 3;

    float acc[3][3];
#pragma unroll
    for (int i = 0; i < 3; i++)
#pragma unroll
        for (int j = 0; j < 3; j++) acc[i][j] = 0.f;
    float ss = 0.f;

    const int n0base = split * 2048;
    for (int nc = 0; nc < 2048; nc += 128) {
        const long n0 = n0base + nc;
        const unsigned short* src = nullptr;
        float* dstrow = nullptr;
        if (t < 24)               { src = Q  + (long)t * N_PIX + n0;        dstrow = Qc[t]; }
        else if (t >= 32 && t < 56) { src = Kr + (long)(t - 32) * N_PIX + n0; dstrow = Kc[t - 32]; }
        if (src) {
#pragma unroll 4
            for (int i = 0; i < 16; i++) {
                int4 raw = *(const int4*)(src + i * 8);
                float f[8];
                f[0] = bf2f((unsigned short)(raw.x & 0xffff)); f[1] = bf2f((unsigned short)((unsigned)raw.x >> 16));
                f[2] = bf2f((unsigned short)(raw.y & 0xffff)); f[3] = bf2f((unsigned short)((unsigned)raw.y >> 16));
                f[4] = bf2f((unsigned short)(raw.z & 0xffff)); f[5] = bf2f((unsigned short)((unsigned)raw.z >> 16));
                f[6] = bf2f((unsigned short)(raw.w & 0xffff)); f[7] = bf2f((unsigned short)((unsigned)raw.w >> 16));
                *(float4*)&dstrow[i * 8]     = make_float4(f[0], f[1], f[2], f[3]);
                *(float4*)&dstrow[i * 8 + 4] = make_float4(f[4], f[5], f[6], f[7]);
#pragma unroll
                for (int q = 0; q < 8; q++) ss = fmaf(f[q], f[q], ss);
            }
        }
        __syncthreads();
#pragma unroll 4
        for (int kk = 0; kk < 128; kk += 4) {
            float4 qv[3], kv[3];
#pragma unroll
            for (int i = 0; i < 3; i++) qv[i] = *(const float4*)&Qc[c0 + i][kk];
#pragma unroll
            for (int j = 0; j < 3; j++) kv[j] = *(const float4*)&Kc[d0 + j][kk];
#pragma unroll
            for (int i = 0; i < 3; i++)
#pragma unroll
                for (int j = 0; j < 3; j++)
                    acc[i][j] += qv[i].x * kv[j].x + qv[i].y * kv[j].y +
                                 qv[i].z * kv[j].z + qv[i].w * kv[j].w;
        }
        __syncthreads();
    }

    const int g = (which * 64 + bh) * 8 + split;
    float* gp = gpart + (long)g * 624;
#pragma unroll
    for (int i = 0; i < 3; i++)
#pragma unroll
        for (int j = 0; j < 3; j++)
            gp[(c0 + i) * 24 + (d0 + j)] = acc[i][j];
    if (t < 24) gp[576 + t] = ss;
    else if (t >= 32 && t < 56) gp[600 + (t - 32)] = ss;
}

// K3b: reduce splits, normalize, temperature, softmax -> P fp32
__global__ __launch_bounds__(256) void gram_reduce_softmax(const float* __restrict__ gpart,
                                                           const float* __restrict__ temperature,
                                                           float* __restrict__ P) {
    const int g = blockIdx.x;           // which*64 + b*8 + head
    const int head = g & 7;
    __shared__ float Gs[576];
    __shared__ float qs[24], ks[24], invq[24], invk[24];

    const int t = threadIdx.x;
    for (int e = t; e < 624; e += 256) {
        float s = 0.f;
        for (int sp = 0; sp < 8; sp++) s += gpart[(long)(g * 8 + sp) * 624 + e];
        if (e < 576) Gs[e] = s;
        else if (e < 600) qs[e - 576] = s;
        else ks[e - 600] = s;
    }
    __syncthreads();
    if (t < 24) {
        invq[t] = 1.f / fmaxf(sqrtf(qs[t]), 1e-12f);
        invk[t] = 1.f / fmaxf(sqrtf(ks[t]), 1e-12f);
    }
    __syncthreads();
    if (t < 24) {
        const float temp = temperature[head];
        float row[24];
        float m = -1e30f;
#pragma unroll
        for (int d = 0; d < 24; d++) {
            row[d] = Gs[t * 24 + d] * invq[t] * invk[d] * temp;
            m = fmaxf(m, row[d]);
        }
        float ssum = 0.f;
#pragma unroll
        for (int d = 0; d < 24; d++) {
            row[d] = expf(row[d] - m);
            ssum += row[d];
        }
        const float inv = 1.f / ssum;
#pragma unroll
        for (int d = 0; d < 24; d++)
            P[(long)g * 576 + t * 24 + d] = row[d] * inv;
    }
}

// K4: weff_bf[o][b] = wproj @ blockdiag(P[1-o][b])  (bf16 out)
__global__ __launch_bounds__(256) void build_weff(const float* __restrict__ wproj,
                                                  const float* __restrict__ P,
                                                  unsigned short* __restrict__ weff) {
    const int o = blockIdx.z, b = blockIdx.y;
    const int e = blockIdx.x * 256 + threadIdx.x;   // 0..36863
    const int co = e / 192, col = e % 192;
    const int head = col / 24, d = col % 24;
    const int which = 1 - o;
    const float* Pp = P + (long)(which * 64 + b * 8 + head) * 576;
    const float* wp = wproj + co * 192 + head * 24;
    float acc = 0.f;
#pragma unroll
    for (int hc = 0; hc < 24; hc++)
        acc = fmaf(wp[hc], Pp[hc * 24 + d], acc);
    weff[((long)(o * 8 + b) * 192 + co) * 192 + col] = f2bf(acc);
}

extern "C" void kernel_launch(void* const* d_in, const int* in_sizes, int n_in,
                              void* d_out, int out_size, void* d_ws, size_t ws_size,
                              hipStream_t stream) {
    (void)in_sizes; (void)n_in; (void)out_size; (void)ws_size;
    const float* rgb    = (const float*)d_in[0];
    const float* ir     = (const float*)d_in[1];
    const float* w_qkv  = (const float*)d_in[2];
    const float* w_dw   = (const float*)d_in[3];
    const float* w_proj = (const float*)d_in[4];
    const float* temp   = (const float*)d_in[5];
    float* out = (float*)d_out;

    char* wsb = (char*)d_ws;
    unsigned short* Y_bf    = (unsigned short*)(wsb);                 // 301,989,888 B
    unsigned short* Z_bf    = (unsigned short*)(wsb + 301989888L);    // 301,989,888 B
    unsigned short* xT_bf   = Z_bf;                                   // alias: dead once dwconv writes Z
    unsigned short* w_bf    = (unsigned short*)(wsb + 603979776L);    //     221,184 B
    unsigned short* weff_bf = (unsigned short*)(wsb + 604200960L);    //   1,179,648 B
    float*          gpart   = (float*)(wsb + 605380608L);             //   2,555,904 B
    float*          P       = (float*)(wsb + 607936512L);             //     294,912 B

    cvt_f32_bf16<<<108, 256, 0, stream>>>(w_qkv, w_bf, 27648);
    cvtT<<<dim3(128, 16), 256, 0, stream>>>(rgb, ir, xT_bf);
    qkv_mfma<<<dim3(128, 3, 16), 512, 0, stream>>>(w_bf, xT_bf, Y_bf);
    dwconv3x3<<<dim3(8, 576, 16), 256, 0, stream>>>(Y_bf, w_dw, Z_bf);
    gram_partial<<<dim3(8, 64, 2), 64, 0, stream>>>(Z_bf, gpart);
    gram_reduce_softmax<<<128, 256, 0, stream>>>(gpart, temp, P);
    build_weff<<<dim3(144, 8, 2), 256, 0, stream>>>(w_proj, P, weff_bf);
    out_mfma<<<dim3(128, 1, 16), 512, 0, stream>>>(weff_bf, Z_bf, out);
}

// Round 8
// 753.675 us; speedup vs baseline: 1.1846x; 1.0607x over previous
//
#include <hip/hip_runtime.h>

#define N_PIX 16384   // 128*128
#define CC    192
#define C3    576
#define KK    192     // GEMM K (=CC)
#define HD    24
#define GSPLIT 32     // gram K-split

typedef __attribute__((ext_vector_type(8))) short short8;   // 8 bf16 = 4 VGPR
typedef __attribute__((ext_vector_type(4))) float f32x4;    // MFMA acc

__device__ __forceinline__ unsigned short f2bf(float x) {
    unsigned u = __float_as_uint(x);
    u += 0x7fff + ((u >> 16) & 1);          // round-to-nearest-even
    return (unsigned short)(u >> 16);
}
__device__ __forceinline__ float bf2f(unsigned short s) {
    return __uint_as_float(((unsigned)s) << 16);
}
__device__ __forceinline__ int pack2(unsigned short lo, unsigned short hi) {
    return (int)(((unsigned)hi << 16) | (unsigned)lo);
}

// async global->LDS, 16B per lane; lds dest is wave-uniform base + lane*16
__device__ __forceinline__ void g2l16(const unsigned short* g, unsigned short* l) {
    __builtin_amdgcn_global_load_lds(
        (const __attribute__((address_space(1))) void*)g,
        (__attribute__((address_space(3))) void*)l, 16, 0, 0);
}

// K0: fp32 -> bf16 bulk convert (vector of 4)
__global__ __launch_bounds__(256) void cvt_f32_bf16(const float* __restrict__ src,
                                                    unsigned short* __restrict__ dst, int n4) {
    int i = blockIdx.x * 256 + threadIdx.x;
    if (i < n4) {
        float4 v = ((const float4*)src)[i];
        ushort4 o;
        o.x = f2bf(v.x); o.y = f2bf(v.y); o.z = f2bf(v.z); o.w = f2bf(v.w);
        ((ushort4*)dst)[i] = o;
    }
}

// tiny zero-init
__global__ __launch_bounds__(256) void zero_f32(float* __restrict__ p, int n) {
    int i = blockIdx.x * 256 + threadIdx.x;
    if (i < n) p[i] = 0.f;
}

// K0b: transpose+convert x[z][192][16384] fp32 -> xT[z][16384][192] bf16.
__global__ __launch_bounds__(256) void cvtT(const float* __restrict__ rgb,
                                            const float* __restrict__ ir,
                                            unsigned short* __restrict__ xT) {
    const int z  = blockIdx.y;
    const int n0 = blockIdx.x * 128;
    const float* x = ((z >= 8) ? ir : rgb) + (long)(z & 7) * CC * N_PIX;
    __shared__ unsigned short T[192][136];

    const int t = threadIdx.x;
#pragma unroll
    for (int i = 0; i < 24; i++) {
        int q = i * 256 + t;
        int k = q >> 5, nc = q & 31;
        float4 v = *(const float4*)(x + (long)k * N_PIX + n0 + nc * 4);
        ushort4 o;
        o.x = f2bf(v.x); o.y = f2bf(v.y); o.z = f2bf(v.z); o.w = f2bf(v.w);
        *(ushort4*)&T[k][nc * 4] = o;
    }
    __syncthreads();
    unsigned short* dst = xT + ((long)z * N_PIX + n0) * CC;
#pragma unroll
    for (int i = 0; i < 12; i++) {
        int c = i * 256 + t;
        int n = c / 24, kc = c - n * 24;
        unsigned short us[8];
#pragma unroll
        for (int j = 0; j < 8; j++) us[j] = T[kc * 8 + j][n];
        int4 pk = make_int4(pack2(us[0], us[1]), pack2(us[2], us[3]),
                            pack2(us[4], us[5]), pack2(us[6], us[7]));
        *(int4*)(dst + (long)n * CC + kc * 8) = pk;
    }
}

// ---------------------------------------------------------------------------
// qkv v5: Y[z][576,16384] = w_bf[576,192] @ xT[z][16384,192]^T
// 512 thr = 8 waves (2x4), wave tile 96x32, acc[6][2]. K-step 64, 3 iters.
// Double-buffered LDS, global_load_lds staging, 3-bit chunk-XOR swizzle.
// ---------------------------------------------------------------------------
__global__ __launch_bounds__(512, 4) void qkv_mfma(const unsigned short* __restrict__ wbf,
                                                   const unsigned short* __restrict__ xT,
                                                   unsigned short* __restrict__ Ybf) {
    const int z  = blockIdx.z;
    const unsigned short* Bg = xT + (long)z * N_PIX * CC;   // [n][k] bf16
    unsigned short* y = Ybf + (long)z * C3 * N_PIX;
    const int m0 = blockIdx.y * 192, n0 = blockIdx.x * 128;

    __shared__ unsigned short As[2][192 * 64];
    __shared__ unsigned short Bs[2][128 * 64];

    const int tid  = threadIdx.x;
    const int wave = tid >> 6, lane = tid & 63;
    const int quad = lane >> 4, l15 = lane & 15;
    const int wr = wave >> 2, wc = wave & 3;   // 2 x 4 wave grid

    f32x4 acc[6][2];
#pragma unroll
    for (int i = 0; i < 6; i++)
#pragma unroll
        for (int j = 0; j < 2; j++) acc[i][j] = (f32x4)0.f;

    auto stage = [&](int buf, int k0) {
#pragma unroll
        for (int s = 0; s < 3; s++) {
            int j = s * 8 + wave;
            int q = j * 64 + lane;
            int m = q >> 3, c = (q & 7) ^ (m & 7);
            g2l16(wbf + (long)(m0 + m) * KK + k0 + c * 8, &As[buf][j * 512]);
        }
#pragma unroll
        for (int s = 0; s < 2; s++) {
            int j = s * 8 + wave;
            int q = j * 64 + lane;
            int n = q >> 3, c = (q & 7) ^ (n & 7);
            g2l16(Bg + (long)(n0 + n) * CC + k0 + c * 8, &Bs[buf][j * 512]);
        }
    };

    stage(0, 0);
    __syncthreads();
    int cur = 0;
    for (int it = 0; it < 3; ++it) {
        if (it < 2) stage(cur ^ 1, (it + 1) * 64);
        const unsigned short* A  = As[cur];
        const unsigned short* Bl = Bs[cur];
#pragma unroll
        for (int kk = 0; kk < 2; kk++) {
            short8 a[6], b[2];
#pragma unroll
            for (int mi = 0; mi < 6; mi++) {
                int r = wr * 96 + mi * 16 + l15;
                int c = (kk * 4 + quad) ^ (r & 7);
                a[mi] = *(const short8*)&A[r * 64 + c * 8];
            }
#pragma unroll
            for (int ni = 0; ni < 2; ni++) {
                int n = wc * 32 + ni * 16 + l15;
                int c = (kk * 4 + quad) ^ (n & 7);
                b[ni] = *(const short8*)&Bl[n * 64 + c * 8];
            }
#pragma unroll
            for (int mi = 0; mi < 6; mi++)
#pragma unroll
                for (int ni = 0; ni < 2; ni++)
                    acc[mi][ni] = __builtin_amdgcn_mfma_f32_16x16x32_bf16(a[mi], b[ni], acc[mi][ni], 0, 0, 0);
        }
        __syncthreads();
        cur ^= 1;
    }

#pragma unroll
    for (int mi = 0; mi < 6; mi++)
#pragma unroll
        for (int ni = 0; ni < 2; ni++)
#pragma unroll
            for (int r = 0; r < 4; r++) {
                int row = m0 + wr * 96 + mi * 16 + quad * 4 + r;
                int col = n0 + wc * 32 + ni * 16 + l15;
                y[(long)row * N_PIX + col] = f2bf(acc[mi][ni][r]);
            }
}

// ---------------------------------------------------------------------------
// gram v3 (MFMA): per (which,b): G[192,192] = Q[192,N] @ K[192,N]^T, K-split 32.
// Both operands row-major, pixel-contiguous -> v5 staging pattern, no transpose.
// 512 thr = 8 waves (4x2), wave tile 48x96, acc[3][6]. K-step 64, 8 iters.
// Only the 8 per-head 24x24 diagonal blocks are stored (compacted).
// ---------------------------------------------------------------------------
__global__ __launch_bounds__(512, 2) void gram_mfma(const unsigned short* __restrict__ Zbf,
                                                    float* __restrict__ gpart) {
    const int ks = blockIdx.x;          // 0..31
    const int zp = blockIdx.y;          // which*8 + b
    const int which = zp >> 3, b = zp & 7;
    const int zq = which ? 8 + b : b;
    const int zk = which ? b : 8 + b;
    const unsigned short* Qg = Zbf + (long)zq * C3 * N_PIX;          // q chans 0..191
    const unsigned short* Kg = Zbf + ((long)zk * C3 + CC) * N_PIX;   // k chans 0..191

    __shared__ unsigned short Qs[2][192 * 64];
    __shared__ unsigned short Ks[2][192 * 64];

    const int tid  = threadIdx.x;
    const int wave = tid >> 6, lane = tid & 63;
    const int quad = lane >> 4, l15 = lane & 15;
    const int wr = wave >> 1, wc = wave & 1;   // 4 x 2 wave grid

    f32x4 acc[3][6];
#pragma unroll
    for (int i = 0; i < 3; i++)
#pragma unroll
        for (int j = 0; j < 6; j++) acc[i][j] = (f32x4)0.f;

    const int base = ks * 512;

    auto stage = [&](int buf, int k0) {
#pragma unroll
        for (int s = 0; s < 3; s++) {
            int j = s * 8 + wave;
            int q = j * 64 + lane;
            int m = q >> 3, c = (q & 7) ^ (m & 7);
            g2l16(Qg + (long)m * N_PIX + k0 + c * 8, &Qs[buf][j * 512]);
            g2l16(Kg + (long)m * N_PIX + k0 + c * 8, &Ks[buf][j * 512]);
        }
    };

    stage(0, base);
    __syncthreads();
    int cur = 0;
    for (int it = 0; it < 8; ++it) {
        if (it < 7) stage(cur ^ 1, base + (it + 1) * 64);
        const unsigned short* Q = Qs[cur];
        const unsigned short* Kl = Ks[cur];
#pragma unroll
        for (int kk = 0; kk < 2; kk++) {
            short8 a[3], bf[6];
#pragma unroll
            for (int mi = 0; mi < 3; mi++) {
                int r = wr * 48 + mi * 16 + l15;
                int c = (kk * 4 + quad) ^ (r & 7);
                a[mi] = *(const short8*)&Q[r * 64 + c * 8];
            }
#pragma unroll
            for (int ni = 0; ni < 6; ni++) {
                int n = wc * 96 + ni * 16 + l15;
                int c = (kk * 4 + quad) ^ (n & 7);
                bf[ni] = *(const short8*)&Kl[n * 64 + c * 8];
            }
#pragma unroll
            for (int mi = 0; mi < 3; mi++)
#pragma unroll
                for (int ni = 0; ni < 6; ni++)
                    acc[mi][ni] = __builtin_amdgcn_mfma_f32_16x16x32_bf16(a[mi], bf[ni], acc[mi][ni], 0, 0, 0);
        }
        __syncthreads();
        cur ^= 1;
    }

    // store only diag 24x24 head blocks, compacted: [zp][ks][head][24][24]
#pragma unroll
    for (int mi = 0; mi < 3; mi++)
#pragma unroll
        for (int ni = 0; ni < 6; ni++)
#pragma unroll
            for (int r = 0; r < 4; r++) {
                int row = wr * 48 + mi * 16 + quad * 4 + r;
                int col = wc * 96 + ni * 16 + l15;
                int hr = row / 24, hc = col / 24;
                if (hr == hc)
                    gpart[(((long)zp * GSPLIT + ks) * 8 + hr) * 576 +
                          (row - hr * 24) * 24 + (col - hc * 24)] = acc[mi][ni][r];
            }
}

// ---------------------------------------------------------------------------
// old GEMM body — used by out_mfma.
// ---------------------------------------------------------------------------
__device__ __forceinline__ void mfma_gemm_old(const unsigned short* __restrict__ Abf,
                                              const unsigned short* __restrict__ Bsrc,
                                              float* __restrict__ Cdst,
                                              int m0, int n0) {
    __shared__ unsigned short As[192][44];
    __shared__ unsigned short Bs[128][44];

    const int tid  = threadIdx.x;
    const int wave = tid >> 6, lane = tid & 63;
    const int quad = lane >> 4, l15 = lane & 15;
    const int wr = wave >> 2, wc = wave & 3;

    f32x4 acc[6][2];
#pragma unroll
    for (int i = 0; i < 6; i++)
#pragma unroll
        for (int j = 0; j < 2; j++) acc[i][j] = (f32x4)0.f;

    const int kg = tid & 7;
    const int n2 = tid >> 3;

    for (int k0 = 0; k0 < KK; k0 += 32) {
        {
            int row = tid >> 2, kc = (tid & 3) * 8;
            *(int4*)&As[row][kc] = *(const int4*)(Abf + (long)(m0 + row) * KK + k0 + kc);
            if (tid < 256) {
                int ch = tid + 512;
                int row2 = ch >> 2, kc2 = (ch & 3) * 8;
                *(int4*)&As[row2][kc2] = *(const int4*)(Abf + (long)(m0 + row2) * KK + k0 + kc2);
            }
        }
        {
            ushort2 v[4];
#pragma unroll
            for (int j = 0; j < 4; j++)
                v[j] = *(const ushort2*)(Bsrc + (long)(k0 + kg * 4 + j) * N_PIX + n0 + n2 * 2);
#pragma unroll
            for (int i = 0; i < 2; i++) {
                unsigned short us[4];
#pragma unroll
                for (int j = 0; j < 4; j++) us[j] = i ? v[j].y : v[j].x;
                int2 pk = make_int2(pack2(us[0], us[1]), pack2(us[2], us[3]));
                *(int2*)&Bs[n2 * 2 + i][kg * 4] = pk;
            }
        }
        __syncthreads();

        short8 a[6], b[2];
#pragma unroll
        for (int mi = 0; mi < 6; mi++)
            a[mi] = *(const short8*)&As[wr * 96 + mi * 16 + l15][quad * 8];
#pragma unroll
        for (int ni = 0; ni < 2; ni++)
            b[ni] = *(const short8*)&Bs[wc * 32 + ni * 16 + l15][quad * 8];
#pragma unroll
        for (int mi = 0; mi < 6; mi++)
#pragma unroll
            for (int ni = 0; ni < 2; ni++)
                acc[mi][ni] = __builtin_amdgcn_mfma_f32_16x16x32_bf16(a[mi], b[ni], acc[mi][ni], 0, 0, 0);
        __syncthreads();
    }

#pragma unroll
    for (int mi = 0; mi < 6; mi++)
#pragma unroll
        for (int ni = 0; ni < 2; ni++)
#pragma unroll
            for (int r = 0; r < 4; r++) {
                int row = m0 + wr * 96 + mi * 16 + quad * 4 + r;
                int col = n0 + wc * 32 + ni * 16 + l15;
                Cdst[(long)row * N_PIX + col] = acc[mi][ni][r];
            }
}

// K5: out[z][192,N] = weff_bf[z][192,192] @ V[z][192,N], fp32 out
__global__ __launch_bounds__(512, 4) void out_mfma(const unsigned short* __restrict__ weff,
                                                   const unsigned short* __restrict__ Zbf,
                                                   float* __restrict__ out) {
    const int z = blockIdx.z;
    const unsigned short* V = Zbf + ((long)z * C3 + 2 * CC) * N_PIX;
    float* C = out + (long)z * CC * N_PIX;
    mfma_gemm_old(weff + (long)z * CC * CC, V, C, 0, blockIdx.x * 128);
}

// K2: depthwise 3x3 SAME, bf16 in/out, 8 px/thread + fused channel sum-of-squares.
__global__ __launch_bounds__(256) void dwconv3x3(const unsigned short* __restrict__ Ybf,
                                                 const float* __restrict__ wdw,
                                                 unsigned short* __restrict__ Zbf,
                                                 float* __restrict__ norm) {
    const int z  = blockIdx.z;
    const int oc = blockIdx.y;
    const int idx = blockIdx.x * 256 + threadIdx.x;   // 0..2047
    const int p0  = idx * 8;
    const int h   = p0 >> 7;
    const int w0  = p0 & 127;
    const int wq  = threadIdx.x & 15;
    const unsigned short* Yc = Ybf + ((long)z * C3 + oc) * N_PIX;

    float wk[9];
#pragma unroll
    for (int i = 0; i < 9; i++) wk[i] = wdw[oc * 9 + i];

    float f[3][8];
#pragma unroll
    for (int ry = 0; ry < 3; ry++) {
        const int hy = h + ry - 1;
        int4 raw = make_int4(0, 0, 0, 0);
        if (hy >= 0 && hy <= 127)
            raw = *(const int4*)(Yc + hy * 128 + w0);
        f[ry][0] = bf2f((unsigned short)(raw.x & 0xffff));
        f[ry][1] = bf2f((unsigned short)((unsigned)raw.x >> 16));
        f[ry][2] = bf2f((unsigned short)(raw.y & 0xffff));
        f[ry][3] = bf2f((unsigned short)((unsigned)raw.y >> 16));
        f[ry][4] = bf2f((unsigned short)(raw.z & 0xffff));
        f[ry][5] = bf2f((unsigned short)((unsigned)raw.z >> 16));
        f[ry][6] = bf2f((unsigned short)(raw.w & 0xffff));
        f[ry][7] = bf2f((unsigned short)((unsigned)raw.w >> 16));
    }

    float acc[8];
#pragma unroll
    for (int j = 0; j < 8; j++) acc[j] = 0.f;

#pragma unroll
    for (int ry = 0; ry < 3; ry++) {
        float l = __shfl_up(f[ry][7], 1);
        float r = __shfl_down(f[ry][0], 1);
        if (wq == 0)  l = 0.f;
        if (wq == 15) r = 0.f;
        const float wl = wk[ry * 3 + 0], wc = wk[ry * 3 + 1], wr = wk[ry * 3 + 2];
        acc[0] = fmaf(wl, l, acc[0]);
#pragma unroll
        for (int j = 1; j < 8; j++) acc[j] = fmaf(wl, f[ry][j - 1], acc[j]);
#pragma unroll
        for (int j = 0; j < 8; j++) acc[j] = fmaf(wc, f[ry][j], acc[j]);
#pragma unroll
        for (int j = 0; j < 7; j++) acc[j] = fmaf(wr, f[ry][j + 1], acc[j]);
        acc[7] = fmaf(wr, r, acc[7]);
    }

    ushort4 o[2];
    unsigned short* po = (unsigned short*)o;
#pragma unroll
    for (int j = 0; j < 8; j++) po[j] = f2bf(acc[j]);
    *(int4*)(Zbf + ((long)z * C3 + oc) * N_PIX + p0) = *(const int4*)o;

    // fused norm: sum of squares of the bf16-rounded values (q/k channels only)
    if (oc < 2 * CC) {
        float ss = 0.f;
#pragma unroll
        for (int j = 0; j < 8; j++) {
            float v = bf2f(po[j]);
            ss = fmaf(v, v, ss);
        }
#pragma unroll
        for (int off = 32; off > 0; off >>= 1)
            ss += __shfl_down(ss, off);
        if ((threadIdx.x & 63) == 0)
            atomicAdd(&norm[z * (2 * CC) + oc], ss);
    }
}

// K3b: reduce gram splits, normalize (from fused norms), temperature, softmax -> P
__global__ __launch_bounds__(256) void gram_reduce_softmax(const float* __restrict__ gpart,
                                                           const float* __restrict__ norm,
                                                           const float* __restrict__ temperature,
                                                           float* __restrict__ P) {
    const int g = blockIdx.x;           // which*64 + b*8 + head
    const int which = g >> 6, b = (g >> 3) & 7, head = g & 7;
    const int zp = which * 8 + b;
    const int zq = which ? 8 + b : b;
    const int zk = which ? b : 8 + b;
    __shared__ float Gs[576];
    __shared__ float invq[24], invk[24];

    const int t = threadIdx.x;
    for (int e = t; e < 576; e += 256) {
        float s = 0.f;
        for (int sp = 0; sp < GSPLIT; sp++)
            s += gpart[(((long)zp * GSPLIT + sp) * 8 + head) * 576 + e];
        Gs[e] = s;
    }
    if (t < 24)
        invq[t] = 1.f / fmaxf(sqrtf(norm[zq * (2 * CC) + head * HD + t]), 1e-12f);
    else if (t >= 32 && t < 56)
        invk[t - 32] = 1.f / fmaxf(sqrtf(norm[zk * (2 * CC) + CC + head * HD + (t - 32)]), 1e-12f);
    __syncthreads();
    if (t < 24) {
        const float temp = temperature[head];
        float row[24];
        float m = -1e30f;
#pragma unroll
        for (int d = 0; d < 24; d++) {
            row[d] = Gs[t * 24 + d] * invq[t] * invk[d] * temp;
            m = fmaxf(m, row[d]);
        }
        float ssum = 0.f;
#pragma unroll
        for (int d = 0; d < 24; d++) {
            row[d] = expf(row[d] - m);
            ssum += row[d];
        }
        const float inv = 1.f / ssum;
#pragma unroll
        for (int d = 0; d < 24; d++)
            P[(long)g * 576 + t * 24 + d] = row[d] * inv;
    }
}

// K4: weff_bf[o][b] = wproj @ blockdiag(P[1-o][b])  (bf16 out)
__global__ __launch_bounds__(256) void build_weff(const float* __restrict__ wproj,
                                                  const float* __restrict__ P,
                                                  unsigned short* __restrict__ weff) {
    const int o = blockIdx.z, b = blockIdx.y;
    const int e = blockIdx.x * 256 + threadIdx.x;   // 0..36863
    const int co = e / 192, col = e % 192;
    const int head = col / 24, d = col % 24;
    const int which = 1 - o;
    const float* Pp = P + (long)(which * 64 + b * 8 + head) * 576;
    const float* wp = wproj + co * 192 + head * 24;
    float acc = 0.f;
#pragma unroll
    for (int hc = 0; hc < 24; hc++)
        acc = fmaf(wp[hc], Pp[hc * 24 + d], acc);
    weff[((long)(o * 8 + b) * 192 + co) * 192 + col] = f2bf(acc);
}

extern "C" void kernel_launch(void* const* d_in, const int* in_sizes, int n_in,
                              void* d_out, int out_size, void* d_ws, size_t ws_size,
                              hipStream_t stream) {
    (void)in_sizes; (void)n_in; (void)out_size; (void)ws_size;
    const float* rgb    = (const float*)d_in[0];
    const float* ir     = (const float*)d_in[1];
    const float* w_qkv  = (const float*)d_in[2];
    const float* w_dw   = (const float*)d_in[3];
    const float* w_proj = (const float*)d_in[4];
    const float* temp   = (const float*)d_in[5];
    float* out = (float*)d_out;

    char* wsb = (char*)d_ws;
    unsigned short* Y_bf    = (unsigned short*)(wsb);                 // 301,989,888 B
    unsigned short* Z_bf    = (unsigned short*)(wsb + 301989888L);    // 301,989,888 B
    unsigned short* xT_bf   = Z_bf;                                   // alias: dead once dwconv writes Z
    float*          gpart   = (float*)(wsb);                          // alias Y: dead after dwconv (9.44 MB)
    unsigned short* w_bf    = (unsigned short*)(wsb + 603979776L);    //     221,184 B
    unsigned short* weff_bf = (unsigned short*)(wsb + 604200960L);    //   1,179,648 B
    float*          norm    = (float*)(wsb + 605380608L);             //      24,576 B
    float*          P       = (float*)(wsb + 607936512L);             //     294,912 B

    cvt_f32_bf16<<<108, 256, 0, stream>>>(w_qkv, w_bf, 27648);
    cvtT<<<dim3(128, 16), 256, 0, stream>>>(rgb, ir, xT_bf);
    zero_f32<<<24, 256, 0, stream>>>(norm, 16 * 2 * CC);
    qkv_mfma<<<dim3(128, 3, 16), 512, 0, stream>>>(w_bf, xT_bf, Y_bf);
    dwconv3x3<<<dim3(8, 576, 16), 256, 0, stream>>>(Y_bf, w_dw, Z_bf, norm);
    gram_mfma<<<dim3(GSPLIT, 16), 512, 0, stream>>>(Z_bf, gpart);
    gram_reduce_softmax<<<128, 256, 0, stream>>>(gpart, norm, temp, P);
    build_weff<<<dim3(144, 8, 2), 256, 0, stream>>>(w_proj, P, weff_bf);
    out_mfma<<<dim3(128, 1, 16), 512, 0, stream>>>(weff_bf, Z_bf, out);
}

// Round 9
// 672.953 us; speedup vs baseline: 1.3267x; 1.1200x over previous
//
#include <hip/hip_runtime.h>

#define N_PIX 16384   // 128*128
#define CC    192
#define C3    576
#define KK    192     // GEMM K (=CC)
#define HD    24
#define GSPLIT 32     // gram K-split

typedef __attribute__((ext_vector_type(8))) short short8;   // 8 bf16 = 4 VGPR
typedef __attribute__((ext_vector_type(4))) float f32x4;    // MFMA acc

__device__ __forceinline__ unsigned short f2bf(float x) {
    unsigned u = __float_as_uint(x);
    u += 0x7fff + ((u >> 16) & 1);          // round-to-nearest-even
    return (unsigned short)(u >> 16);
}
__device__ __forceinline__ float bf2f(unsigned short s) {
    return __uint_as_float(((unsigned)s) << 16);
}
__device__ __forceinline__ int pack2(unsigned short lo, unsigned short hi) {
    return (int)(((unsigned)hi << 16) | (unsigned)lo);
}

// async global->LDS, 16B per lane; lds dest is wave-uniform base + lane*16
__device__ __forceinline__ void g2l16(const unsigned short* g, unsigned short* l) {
    __builtin_amdgcn_global_load_lds(
        (const __attribute__((address_space(1))) void*)g,
        (__attribute__((address_space(3))) void*)l, 16, 0, 0);
}

// K0: fp32 -> bf16 bulk convert (vector of 4) — weights only
__global__ __launch_bounds__(256) void cvt_f32_bf16(const float* __restrict__ src,
                                                    unsigned short* __restrict__ dst, int n4) {
    int i = blockIdx.x * 256 + threadIdx.x;
    if (i < n4) {
        float4 v = ((const float4*)src)[i];
        ushort4 o;
        o.x = f2bf(v.x); o.y = f2bf(v.y); o.z = f2bf(v.z); o.w = f2bf(v.w);
        ((ushort4*)dst)[i] = o;
    }
}

// ---------------------------------------------------------------------------
// qkv v6 (direct): Y[z][576,16384] = w_bf[576,192] @ x[z][192,16384]  (fp32 B)
// 512 thr = 8 waves (2x4), wave tile 96x32, acc[6][2]. K-step 64, 3 iters.
// A: g2l16 async double-buffered (3-bit chunk-XOR swizzle).
// B: fp32 loads -> regs (coalesced 512B/wave rows), cvt+pack, swizzled ds_write
//    placed AFTER the MFMA cluster (T14: HBM latency hides under compute).
// Grid (3,128,16): the 3 m-groups sharing one B-slice are consecutive blocks.
// ---------------------------------------------------------------------------
__global__ __launch_bounds__(512, 4) void qkv_mfma(const unsigned short* __restrict__ wbf,
                                                   const float* __restrict__ rgb,
                                                   const float* __restrict__ ir,
                                                   unsigned short* __restrict__ Ybf) {
    const int z = blockIdx.z;
    const float* xg = ((z >= 8) ? ir : rgb) + (long)(z & 7) * CC * N_PIX;
    unsigned short* y = Ybf + (long)z * C3 * N_PIX;
    const int m0 = blockIdx.x * 192, n0 = blockIdx.y * 128;

    __shared__ unsigned short As[2][192 * 64];
    __shared__ unsigned short Bs[2][128 * 64];

    const int tid  = threadIdx.x;
    const int wave = tid >> 6, lane = tid & 63;
    const int quad = lane >> 4, l15 = lane & 15;
    const int wr = wave >> 2, wc = wave & 3;   // 2 x 4 wave grid

    f32x4 acc[6][2];
#pragma unroll
    for (int i = 0; i < 6; i++)
#pragma unroll
        for (int j = 0; j < 2; j++) acc[i][j] = (f32x4)0.f;

    // B staging: nq = col-pair (wave-contiguous -> coalesced), kq = k-chunk of 8
    const int nq = tid & 63, kq = tid >> 6;

    auto stageA = [&](int buf, int k0) {
#pragma unroll
        for (int s = 0; s < 3; s++) {
            int j = s * 8 + wave;
            int q = j * 64 + lane;
            int m = q >> 3, c = (q & 7) ^ (m & 7);
            g2l16(wbf + (long)(m0 + m) * KK + k0 + c * 8, &As[buf][j * 512]);
        }
    };

    float2 bv[8];
    auto loadB = [&](int k0) {
#pragma unroll
        for (int j = 0; j < 8; j++)
            bv[j] = *(const float2*)(xg + (long)(k0 + kq * 8 + j) * N_PIX + n0 + nq * 2);
    };
    auto writeB = [&](int buf) {
#pragma unroll
        for (int i = 0; i < 2; i++) {
            int n = nq * 2 + i;
            unsigned short us[8];
#pragma unroll
            for (int j = 0; j < 8; j++) us[j] = f2bf(i ? bv[j].y : bv[j].x);
            int4 pk = make_int4(pack2(us[0], us[1]), pack2(us[2], us[3]),
                                pack2(us[4], us[5]), pack2(us[6], us[7]));
            int c = kq ^ (n & 7);
            *(int4*)&Bs[buf][n * 64 + c * 8] = pk;
        }
    };

    // prologue
    loadB(0);
    stageA(0, 0);
    writeB(0);                // waits vmcnt for B loads
    __syncthreads();          // drains A g2l16 as well

    int cur = 0;
    for (int it = 0; it < 3; ++it) {
        if (it < 2) {
            stageA(cur ^ 1, (it + 1) * 64);
            loadB((it + 1) * 64);        // in flight across the MFMA cluster
        }
        const unsigned short* A  = As[cur];
        const unsigned short* Bl = Bs[cur];
#pragma unroll
        for (int kk = 0; kk < 2; kk++) {
            short8 a[6], b[2];
#pragma unroll
            for (int mi = 0; mi < 6; mi++) {
                int r = wr * 96 + mi * 16 + l15;
                int c = (kk * 4 + quad) ^ (r & 7);
                a[mi] = *(const short8*)&A[r * 64 + c * 8];
            }
#pragma unroll
            for (int ni = 0; ni < 2; ni++) {
                int n = wc * 32 + ni * 16 + l15;
                int c = (kk * 4 + quad) ^ (n & 7);
                b[ni] = *(const short8*)&Bl[n * 64 + c * 8];
            }
#pragma unroll
            for (int mi = 0; mi < 6; mi++)
#pragma unroll
                for (int ni = 0; ni < 2; ni++)
                    acc[mi][ni] = __builtin_amdgcn_mfma_f32_16x16x32_bf16(a[mi], b[ni], acc[mi][ni], 0, 0, 0);
        }
        if (it < 2) writeB(cur ^ 1);     // convert + LDS write into next buffer
        __syncthreads();
        cur ^= 1;
    }

    // epilogue: C/D layout col=lane&15, row=quad*4+reg
#pragma unroll
    for (int mi = 0; mi < 6; mi++)
#pragma unroll
        for (int ni = 0; ni < 2; ni++)
#pragma unroll
            for (int r = 0; r < 4; r++) {
                int row = m0 + wr * 96 + mi * 16 + quad * 4 + r;
                int col = n0 + wc * 32 + ni * 16 + l15;
                y[(long)row * N_PIX + col] = f2bf(acc[mi][ni][r]);
            }
}

// ---------------------------------------------------------------------------
// gram v3 (MFMA): per (which,b): G[192,192] = Q[192,N] @ K[192,N]^T, K-split 32.
// 512 thr = 8 waves (4x2), wave tile 48x96, acc[3][6]. K-step 64, 8 iters.
// Only the 8 per-head 24x24 diagonal blocks are stored (compacted).
// ---------------------------------------------------------------------------
__global__ __launch_bounds__(512, 2) void gram_mfma(const unsigned short* __restrict__ Zbf,
                                                    float* __restrict__ gpart) {
    const int ks = blockIdx.x;          // 0..31
    const int zp = blockIdx.y;          // which*8 + b
    const int which = zp >> 3, b = zp & 7;
    const int zq = which ? 8 + b : b;
    const int zk = which ? b : 8 + b;
    const unsigned short* Qg = Zbf + (long)zq * C3 * N_PIX;          // q chans 0..191
    const unsigned short* Kg = Zbf + ((long)zk * C3 + CC) * N_PIX;   // k chans 0..191

    __shared__ unsigned short Qs[2][192 * 64];
    __shared__ unsigned short Ks[2][192 * 64];

    const int tid  = threadIdx.x;
    const int wave = tid >> 6, lane = tid & 63;
    const int quad = lane >> 4, l15 = lane & 15;
    const int wr = wave >> 1, wc = wave & 1;   // 4 x 2 wave grid

    f32x4 acc[3][6];
#pragma unroll
    for (int i = 0; i < 3; i++)
#pragma unroll
        for (int j = 0; j < 6; j++) acc[i][j] = (f32x4)0.f;

    const int base = ks * 512;

    auto stage = [&](int buf, int k0) {
#pragma unroll
        for (int s = 0; s < 3; s++) {
            int j = s * 8 + wave;
            int q = j * 64 + lane;
            int m = q >> 3, c = (q & 7) ^ (m & 7);
            g2l16(Qg + (long)m * N_PIX + k0 + c * 8, &Qs[buf][j * 512]);
            g2l16(Kg + (long)m * N_PIX + k0 + c * 8, &Ks[buf][j * 512]);
        }
    };

    stage(0, base);
    __syncthreads();
    int cur = 0;
    for (int it = 0; it < 8; ++it) {
        if (it < 7) stage(cur ^ 1, base + (it + 1) * 64);
        const unsigned short* Q = Qs[cur];
        const unsigned short* Kl = Ks[cur];
#pragma unroll
        for (int kk = 0; kk < 2; kk++) {
            short8 a[3], bf[6];
#pragma unroll
            for (int mi = 0; mi < 3; mi++) {
                int r = wr * 48 + mi * 16 + l15;
                int c = (kk * 4 + quad) ^ (r & 7);
                a[mi] = *(const short8*)&Q[r * 64 + c * 8];
            }
#pragma unroll
            for (int ni = 0; ni < 6; ni++) {
                int n = wc * 96 + ni * 16 + l15;
                int c = (kk * 4 + quad) ^ (n & 7);
                bf[ni] = *(const short8*)&Kl[n * 64 + c * 8];
            }
#pragma unroll
            for (int mi = 0; mi < 3; mi++)
#pragma unroll
                for (int ni = 0; ni < 6; ni++)
                    acc[mi][ni] = __builtin_amdgcn_mfma_f32_16x16x32_bf16(a[mi], bf[ni], acc[mi][ni], 0, 0, 0);
        }
        __syncthreads();
        cur ^= 1;
    }

    // store only diag 24x24 head blocks, compacted: [zp][ks][head][24][24]
#pragma unroll
    for (int mi = 0; mi < 3; mi++)
#pragma unroll
        for (int ni = 0; ni < 6; ni++)
#pragma unroll
            for (int r = 0; r < 4; r++) {
                int row = wr * 48 + mi * 16 + quad * 4 + r;
                int col = wc * 96 + ni * 16 + l15;
                int hr = row / 24, hc = col / 24;
                if (hr == hc)
                    gpart[(((long)zp * GSPLIT + ks) * 8 + hr) * 576 +
                          (row - hr * 24) * 24 + (col - hc * 24)] = acc[mi][ni][r];
            }
}

// ---------------------------------------------------------------------------
// old GEMM body — used by out_mfma.
// ---------------------------------------------------------------------------
__device__ __forceinline__ void mfma_gemm_old(const unsigned short* __restrict__ Abf,
                                              const unsigned short* __restrict__ Bsrc,
                                              float* __restrict__ Cdst,
                                              int m0, int n0) {
    __shared__ unsigned short As[192][44];
    __shared__ unsigned short Bs[128][44];

    const int tid  = threadIdx.x;
    const int wave = tid >> 6, lane = tid & 63;
    const int quad = lane >> 4, l15 = lane & 15;
    const int wr = wave >> 2, wc = wave & 3;

    f32x4 acc[6][2];
#pragma unroll
    for (int i = 0; i < 6; i++)
#pragma unroll
        for (int j = 0; j < 2; j++) acc[i][j] = (f32x4)0.f;

    const int kg = tid & 7;
    const int n2 = tid >> 3;

    for (int k0 = 0; k0 < KK; k0 += 32) {
        {
            int row = tid >> 2, kc = (tid & 3) * 8;
            *(int4*)&As[row][kc] = *(const int4*)(Abf + (long)(m0 + row) * KK + k0 + kc);
            if (tid < 256) {
                int ch = tid + 512;
                int row2 = ch >> 2, kc2 = (ch & 3) * 8;
                *(int4*)&As[row2][kc2] = *(const int4*)(Abf + (long)(m0 + row2) * KK + k0 + kc2);
            }
        }
        {
            ushort2 v[4];
#pragma unroll
            for (int j = 0; j < 4; j++)
                v[j] = *(const ushort2*)(Bsrc + (long)(k0 + kg * 4 + j) * N_PIX + n0 + n2 * 2);
#pragma unroll
            for (int i = 0; i < 2; i++) {
                unsigned short us[4];
#pragma unroll
                for (int j = 0; j < 4; j++) us[j] = i ? v[j].y : v[j].x;
                int2 pk = make_int2(pack2(us[0], us[1]), pack2(us[2], us[3]));
                *(int2*)&Bs[n2 * 2 + i][kg * 4] = pk;
            }
        }
        __syncthreads();

        short8 a[6], b[2];
#pragma unroll
        for (int mi = 0; mi < 6; mi++)
            a[mi] = *(const short8*)&As[wr * 96 + mi * 16 + l15][quad * 8];
#pragma unroll
        for (int ni = 0; ni < 2; ni++)
            b[ni] = *(const short8*)&Bs[wc * 32 + ni * 16 + l15][quad * 8];
#pragma unroll
        for (int mi = 0; mi < 6; mi++)
#pragma unroll
            for (int ni = 0; ni < 2; ni++)
                acc[mi][ni] = __builtin_amdgcn_mfma_f32_16x16x32_bf16(a[mi], b[ni], acc[mi][ni], 0, 0, 0);
        __syncthreads();
    }

#pragma unroll
    for (int mi = 0; mi < 6; mi++)
#pragma unroll
        for (int ni = 0; ni < 2; ni++)
#pragma unroll
            for (int r = 0; r < 4; r++) {
                int row = m0 + wr * 96 + mi * 16 + quad * 4 + r;
                int col = n0 + wc * 32 + ni * 16 + l15;
                Cdst[(long)row * N_PIX + col] = acc[mi][ni][r];
            }
}

// K5: out[z][192,N] = weff_bf[z][192,192] @ V[z][192,N], fp32 out
__global__ __launch_bounds__(512, 4) void out_mfma(const unsigned short* __restrict__ weff,
                                                   const unsigned short* __restrict__ Zbf,
                                                   float* __restrict__ out) {
    const int z = blockIdx.z;
    const unsigned short* V = Zbf + ((long)z * C3 + 2 * CC) * N_PIX;
    float* C = out + (long)z * CC * N_PIX;
    mfma_gemm_old(weff + (long)z * CC * CC, V, C, 0, blockIdx.x * 128);
}

// K2: depthwise 3x3 SAME, bf16 in/out, 8 px/thread + per-block norm partials
// (no atomics: nrm[z][oc][blk] summed later in gram_reduce_softmax).
__global__ __launch_bounds__(256) void dwconv3x3(const unsigned short* __restrict__ Ybf,
                                                 const float* __restrict__ wdw,
                                                 unsigned short* __restrict__ Zbf,
                                                 float* __restrict__ nrm) {
    const int z  = blockIdx.z;
    const int oc = blockIdx.y;
    const int idx = blockIdx.x * 256 + threadIdx.x;   // 0..2047
    const int p0  = idx * 8;
    const int h   = p0 >> 7;
    const int w0  = p0 & 127;
    const int wq  = threadIdx.x & 15;
    const unsigned short* Yc = Ybf + ((long)z * C3 + oc) * N_PIX;

    float wk[9];
#pragma unroll
    for (int i = 0; i < 9; i++) wk[i] = wdw[oc * 9 + i];

    float f[3][8];
#pragma unroll
    for (int ry = 0; ry < 3; ry++) {
        const int hy = h + ry - 1;
        int4 raw = make_int4(0, 0, 0, 0);
        if (hy >= 0 && hy <= 127)
            raw = *(const int4*)(Yc + hy * 128 + w0);
        f[ry][0] = bf2f((unsigned short)(raw.x & 0xffff));
        f[ry][1] = bf2f((unsigned short)((unsigned)raw.x >> 16));
        f[ry][2] = bf2f((unsigned short)(raw.y & 0xffff));
        f[ry][3] = bf2f((unsigned short)((unsigned)raw.y >> 16));
        f[ry][4] = bf2f((unsigned short)(raw.z & 0xffff));
        f[ry][5] = bf2f((unsigned short)((unsigned)raw.z >> 16));
        f[ry][6] = bf2f((unsigned short)(raw.w & 0xffff));
        f[ry][7] = bf2f((unsigned short)((unsigned)raw.w >> 16));
    }

    float acc[8];
#pragma unroll
    for (int j = 0; j < 8; j++) acc[j] = 0.f;

#pragma unroll
    for (int ry = 0; ry < 3; ry++) {
        float l = __shfl_up(f[ry][7], 1);
        float r = __shfl_down(f[ry][0], 1);
        if (wq == 0)  l = 0.f;
        if (wq == 15) r = 0.f;
        const float wl = wk[ry * 3 + 0], wc = wk[ry * 3 + 1], wr = wk[ry * 3 + 2];
        acc[0] = fmaf(wl, l, acc[0]);
#pragma unroll
        for (int j = 1; j < 8; j++) acc[j] = fmaf(wl, f[ry][j - 1], acc[j]);
#pragma unroll
        for (int j = 0; j < 8; j++) acc[j] = fmaf(wc, f[ry][j], acc[j]);
#pragma unroll
        for (int j = 0; j < 7; j++) acc[j] = fmaf(wr, f[ry][j + 1], acc[j]);
        acc[7] = fmaf(wr, r, acc[7]);
    }

    ushort4 o[2];
    unsigned short* po = (unsigned short*)o;
#pragma unroll
    for (int j = 0; j < 8; j++) po[j] = f2bf(acc[j]);
    *(int4*)(Zbf + ((long)z * C3 + oc) * N_PIX + p0) = *(const int4*)o;

    // block-level sum of squares of the bf16-rounded values (q/k channels only)
    __shared__ float red[4];
    float ss = 0.f;
#pragma unroll
    for (int j = 0; j < 8; j++) {
        float v = bf2f(po[j]);
        ss = fmaf(v, v, ss);
    }
#pragma unroll
    for (int off = 32; off > 0; off >>= 1)
        ss += __shfl_down(ss, off);
    if ((threadIdx.x & 63) == 0) red[threadIdx.x >> 6] = ss;
    __syncthreads();
    if (threadIdx.x == 0 && oc < 2 * CC)
        nrm[((long)z * (2 * CC) + oc) * 8 + blockIdx.x] = red[0] + red[1] + red[2] + red[3];
}

// K3b: reduce gram splits + norm partials, normalize, temperature, softmax -> P
__global__ __launch_bounds__(256) void gram_reduce_softmax(const float* __restrict__ gpart,
                                                           const float* __restrict__ nrm,
                                                           const float* __restrict__ temperature,
                                                           float* __restrict__ P) {
    const int g = blockIdx.x;           // which*64 + b*8 + head
    const int which = g >> 6, b = (g >> 3) & 7, head = g & 7;
    const int zp = which * 8 + b;
    const int zq = which ? 8 + b : b;
    const int zk = which ? b : 8 + b;
    __shared__ float Gs[576];
    __shared__ float invq[24], invk[24];

    const int t = threadIdx.x;
    for (int e = t; e < 576; e += 256) {
        float s = 0.f;
        for (int sp = 0; sp < GSPLIT; sp++)
            s += gpart[(((long)zp * GSPLIT + sp) * 8 + head) * 576 + e];
        Gs[e] = s;
    }
    if (t < 24) {
        float s = 0.f;
#pragma unroll
        for (int b8 = 0; b8 < 8; b8++)
            s += nrm[((long)zq * (2 * CC) + head * HD + t) * 8 + b8];
        invq[t] = 1.f / fmaxf(sqrtf(s), 1e-12f);
    } else if (t >= 32 && t < 56) {
        float s = 0.f;
#pragma unroll
        for (int b8 = 0; b8 < 8; b8++)
            s += nrm[((long)zk * (2 * CC) + CC + head * HD + (t - 32)) * 8 + b8];
        invk[t - 32] = 1.f / fmaxf(sqrtf(s), 1e-12f);
    }
    __syncthreads();
    if (t < 24) {
        const float temp = temperature[head];
        float row[24];
        float m = -1e30f;
#pragma unroll
        for (int d = 0; d < 24; d++) {
            row[d] = Gs[t * 24 + d] * invq[t] * invk[d] * temp;
            m = fmaxf(m, row[d]);
        }
        float ssum = 0.f;
#pragma unroll
        for (int d = 0; d < 24; d++) {
            row[d] = expf(row[d] - m);
            ssum += row[d];
        }
        const float inv = 1.f / ssum;
#pragma unroll
        for (int d = 0; d < 24; d++)
            P[(long)g * 576 + t * 24 + d] = row[d] * inv;
    }
}

// K4: weff_bf[o][b] = wproj @ blockdiag(P[1-o][b])  (bf16 out)
__global__ __launch_bounds__(256) void build_weff(const float* __restrict__ wproj,
                                                  const float* __restrict__ P,
                                                  unsigned short* __restrict__ weff) {
    const int o = blockIdx.z, b = blockIdx.y;
    const int e = blockIdx.x * 256 + threadIdx.x;   // 0..36863
    const int co = e / 192, col = e % 192;
    const int head = col / 24, d = col % 24;
    const int which = 1 - o;
    const float* Pp = P + (long)(which * 64 + b * 8 + head) * 576;
    const float* wp = wproj + co * 192 + head * 24;
    float acc = 0.f;
#pragma unroll
    for (int hc = 0; hc < 24; hc++)
        acc = fmaf(wp[hc], Pp[hc * 24 + d], acc);
    weff[((long)(o * 8 + b) * 192 + co) * 192 + col] = f2bf(acc);
}

extern "C" void kernel_launch(void* const* d_in, const int* in_sizes, int n_in,
                              void* d_out, int out_size, void* d_ws, size_t ws_size,
                              hipStream_t stream) {
    (void)in_sizes; (void)n_in; (void)out_size; (void)ws_size;
    const float* rgb    = (const float*)d_in[0];
    const float* ir     = (const float*)d_in[1];
    const float* w_qkv  = (const float*)d_in[2];
    const float* w_dw   = (const float*)d_in[3];
    const float* w_proj = (const float*)d_in[4];
    const float* temp   = (const float*)d_in[5];
    float* out = (float*)d_out;

    char* wsb = (char*)d_ws;
    unsigned short* Y_bf    = (unsigned short*)(wsb);                 // 301,989,888 B
    unsigned short* Z_bf    = (unsigned short*)(wsb + 301989888L);    // 301,989,888 B
    float*          gpart   = (float*)(wsb);                          // alias Y: dead after dwconv (9.44 MB)
    unsigned short* w_bf    = (unsigned short*)(wsb + 603979776L);    //     221,184 B
    unsigned short* weff_bf = (unsigned short*)(wsb + 604200960L);    //   1,179,648 B
    float*          nrm     = (float*)(wsb + 605380608L);             //     196,608 B
    float*          P       = (float*)(wsb + 607936512L);             //     294,912 B

    cvt_f32_bf16<<<108, 256, 0, stream>>>(w_qkv, w_bf, 27648);
    qkv_mfma<<<dim3(3, 128, 16), 512, 0, stream>>>(w_bf, rgb, ir, Y_bf);
    dwconv3x3<<<dim3(8, 576, 16), 256, 0, stream>>>(Y_bf, w_dw, Z_bf, nrm);
    gram_mfma<<<dim3(GSPLIT, 16), 512, 0, stream>>>(Z_bf, gpart);
    gram_reduce_softmax<<<128, 256, 0, stream>>>(gpart, nrm, temp, P);
    build_weff<<<dim3(144, 8, 2), 256, 0, stream>>>(w_proj, P, weff_bf);
    out_mfma<<<dim3(128, 1, 16), 512, 0, stream>>>(weff_bf, Z_bf, out);
}